// Round 13
// baseline (300.599 us; speedup 1.0000x reference)
//
#include <hip/hip_runtime.h>
#include <hip/hip_bf16.h>
#include <stdint.h>

#define DM 1024
#define DFF 4096
#define NH 16
#define DH 64
#define SEQ 2048
#define MROWS 4096  // B*S

typedef unsigned short u16;
typedef __attribute__((ext_vector_type(8))) short bf16x8;
typedef __attribute__((ext_vector_type(4))) float f32x4;
typedef __attribute__((ext_vector_type(16))) float f32x16;
typedef __attribute__((ext_vector_type(4))) unsigned short u16x4;

__device__ __forceinline__ u16 f2b(float f) {
  union { float f; uint32_t u; } v; v.f = f;
  uint32_t r = v.u + 0x7FFFu + ((v.u >> 16) & 1u);
  return (u16)(r >> 16);
}

// native convert — clang emits v_cvt_pk_bf16_f32 for pairs (RNE)
__device__ __forceinline__ u16 f2bn(float f) {
  __hip_bfloat16 h = __float2bfloat16(f);
  return *reinterpret_cast<u16*>(&h);
}

__device__ __forceinline__ uint32_t pk2(float lo, float hi) {
  return (uint32_t)f2bn(lo) | ((uint32_t)f2bn(hi) << 16);
}

__device__ __forceinline__ void gl_lds16(const void* g, void* l) {
  __builtin_amdgcn_global_load_lds(
      (const __attribute__((address_space(1))) uint32_t*)g,
      (__attribute__((address_space(3))) uint32_t*)l, 16, 0, 0);
}

// ---------------- weight fp32 -> bf16 convert (all 6 weights, one kernel) --
struct CvtArgs { const float* src[6]; u16* dst[6]; int n4[6]; };

__global__ void cvt_kernel(CvtArgs a) {
  const int stride = gridDim.x * blockDim.x;
  const int t0 = blockIdx.x * blockDim.x + threadIdx.x;
  for (int i = 0; i < 6; ++i) {
    const float4* s = (const float4*)a.src[i];
    u16x4* d = (u16x4*)a.dst[i];
    const int n = a.n4[i];
    for (int idx = t0; idx < n; idx += stride) {
      float4 v = s[idx];
      u16x4 o;
      o[0] = f2b(v.x); o[1] = f2b(v.y); o[2] = f2b(v.z); o[3] = f2b(v.w);
      d[idx] = o;
    }
  }
}

// ---------------- fused LayerNorm: fp32 in -> bf16 out ---------------------
__global__ __launch_bounds__(256)
void ln_kernel(const float* __restrict__ x, const float* __restrict__ g,
               const float* __restrict__ be, u16* __restrict__ out) {
  const int row = blockIdx.x;
  const int tid = threadIdx.x;
  const float4 v = ((const float4*)(x + (size_t)row * DM))[tid];
  float s  = v.x + v.y + v.z + v.w;
  float s2 = v.x * v.x + v.y * v.y + v.z * v.z + v.w * v.w;
  #pragma unroll
  for (int m = 1; m < 64; m <<= 1) {
    s  += __shfl_xor(s,  m, 64);
    s2 += __shfl_xor(s2, m, 64);
  }
  __shared__ float red[8];
  const int w = tid >> 6, lane = tid & 63;
  if (lane == 0) { red[w] = s; red[4 + w] = s2; }
  __syncthreads();
  s  = red[0] + red[1] + red[2] + red[3];
  s2 = red[4] + red[5] + red[6] + red[7];
  const float mu  = s * (1.0f / DM);
  const float var = s2 * (1.0f / DM) - mu * mu;
  const float rstd = rsqrtf(var + 1e-5f);
  const float4 gv = ((const float4*)g)[tid];
  const float4 bv = ((const float4*)be)[tid];
  u16x4 o;
  o[0] = f2b((v.x - mu) * rstd * gv.x + bv.x);
  o[1] = f2b((v.y - mu) * rstd * gv.y + bv.y);
  o[2] = f2b((v.z - mu) * rstd * gv.z + bv.z);
  o[3] = f2b((v.w - mu) * rstd * gv.w + bv.w);
  ((u16x4*)(out + (size_t)row * DM))[tid] = o;
}

// ---------------- combine (2-way): out = p0 + p1 + bias + resid (fp32) -----
__global__ __launch_bounds__(256)
void combine_kernel(const float4* __restrict__ p0, const float4* __restrict__ p1,
                    const float4* __restrict__ bias, const float4* __restrict__ resid,
                    float4* __restrict__ out, int total4, int colmask4) {
  for (int i = blockIdx.x * 256 + threadIdx.x; i < total4; i += gridDim.x * 256) {
    float4 a = p0[i], b = p1[i], bs = bias[i & colmask4], rr = resid[i];
    float4 o;
    o.x = a.x + b.x + bs.x + rr.x;
    o.y = a.y + b.y + bs.y + rr.y;
    o.z = a.z + b.z + bs.z + rr.z;
    o.w = a.w + b.w + bs.w + rr.w;
    out[i] = o;
  }
}

// ---------------- combine (4-way): out = Σp + bias + resid (fp32) ----------
__global__ __launch_bounds__(256)
void combine4_kernel(const float4* __restrict__ p0, const float4* __restrict__ p1,
                     const float4* __restrict__ p2, const float4* __restrict__ p3,
                     const float4* __restrict__ bias, const float4* __restrict__ resid,
                     float4* __restrict__ out, int total4, int colmask4) {
  for (int i = blockIdx.x * 256 + threadIdx.x; i < total4; i += gridDim.x * 256) {
    float4 a = p0[i], b = p1[i], c = p2[i], d = p3[i];
    float4 bs = bias[i & colmask4], rr = resid[i];
    float4 o;
    o.x = (a.x + b.x) + (c.x + d.x) + bs.x + rr.x;
    o.y = (a.y + b.y) + (c.y + d.y) + bs.y + rr.y;
    o.z = (a.z + b.z) + (c.z + d.z) + bs.z + rr.z;
    o.w = (a.w + b.w) + (c.w + d.w) + bs.w + rr.w;
    out[i] = o;
  }
}

// ------- fused 4-way combine + LayerNorm: x1 = Σp+bias+resid (fp32 out),
//         norm = LN(x1)*g+b (bf16 out, separate buffer) ---------------------
__global__ __launch_bounds__(256)
void combine4_ln_kernel(const float4* __restrict__ p0, const float4* __restrict__ p1,
                        const float4* __restrict__ p2, const float4* __restrict__ p3,
                        const float4* __restrict__ bias, const float4* __restrict__ resid,
                        float4* __restrict__ xout,
                        const float* __restrict__ g, const float* __restrict__ be,
                        u16* __restrict__ nout) {
  const int row = blockIdx.x;
  const int tid = threadIdx.x;
  const int i = row * (DM / 4) + tid;
  const float4 a = p0[i], b = p1[i], c = p2[i], d = p3[i];
  const float4 bs = bias[tid], rr = resid[i];
  float4 v;
  v.x = (a.x + b.x) + (c.x + d.x) + bs.x + rr.x;
  v.y = (a.y + b.y) + (c.y + d.y) + bs.y + rr.y;
  v.z = (a.z + b.z) + (c.z + d.z) + bs.z + rr.z;
  v.w = (a.w + b.w) + (c.w + d.w) + bs.w + rr.w;
  xout[i] = v;
  float s  = v.x + v.y + v.z + v.w;
  float s2 = v.x * v.x + v.y * v.y + v.z * v.z + v.w * v.w;
  #pragma unroll
  for (int m = 1; m < 64; m <<= 1) {
    s  += __shfl_xor(s,  m, 64);
    s2 += __shfl_xor(s2, m, 64);
  }
  __shared__ float red[8];
  const int w = tid >> 6, lane = tid & 63;
  if (lane == 0) { red[w] = s; red[4 + w] = s2; }
  __syncthreads();
  s  = red[0] + red[1] + red[2] + red[3];
  s2 = red[4] + red[5] + red[6] + red[7];
  const float mu  = s * (1.0f / DM);
  const float var = s2 * (1.0f / DM) - mu * mu;
  const float rstd = rsqrtf(var + 1e-5f);
  const float4 gv = ((const float4*)g)[tid];
  const float4 bv = ((const float4*)be)[tid];
  u16x4 o;
  o[0] = f2b((v.x - mu) * rstd * gv.x + bv.x);
  o[1] = f2b((v.y - mu) * rstd * gv.y + bv.y);
  o[2] = f2b((v.z - mu) * rstd * gv.z + bv.z);
  o[3] = f2b((v.w - mu) * rstd * gv.w + bv.w);
  ((u16x4*)(nout + (size_t)row * DM))[tid] = o;
}

// ---------------- GEMM: C[M,N] = A[M,K](bf16) * W[N,K](bf16)^T + bias ------
// 2-phase double-buffer at BK=32 (guide's verified minimum T3 recipe).
// __launch_bounds__(256,4): total VGPR+AGPR <= 128/wave (unified file).
// LDS swizzle chunk ^= (row>>1)&3 (2-way = free, m136), both-sides (rule #21).
struct GemmPtrs { const u16* W[4]; const float* bias[4]; void* out[4];
                  const float* resid; int vtrans; };

template<int EPI>
__global__ __launch_bounds__(256, 4)
void gemm_bt(const u16* __restrict__ A, GemmPtrs p, int M, int N,
             int Kstride, int Kchunk) {
  __shared__ __align__(16) u16 As[2][128 * 32];
  __shared__ __align__(16) u16 Bs[2][128 * 32];
  const u16* __restrict__ Wm = p.W[blockIdx.z];
  const float* __restrict__ bias = p.bias[blockIdx.z];
  void* outv = p.out[blockIdx.z];
  const float* resid = p.resid;

  const int tid = threadIdx.x;
  const int lane = tid & 63;
  const int w = tid >> 6;
  const int brow = blockIdx.y * 128;
  const int bcol = blockIdx.x * 128;
  const int wr = (w >> 1) * 64, wc = (w & 1) * 64;
  const int koff = (EPI == 3) ? blockIdx.z * Kchunk : 0;

  f32x4 acc[4][4] = {};

  const int srow = tid >> 2;
  const int sc = ((tid & 3) ^ ((tid >> 3) & 3)) * 8;   // elements
  const int ldso = w * 512;                            // u16; +2048 for rows 64+

  const int nt = Kchunk >> 5;

  auto stage = [&](int t) {
    const int sl = t & 1;
    const int k0 = koff + t * 32;
    gl_lds16(&A [(size_t)(brow + srow) * Kstride + k0 + sc],      &As[sl][ldso]);
    gl_lds16(&A [(size_t)(brow + 64 + srow) * Kstride + k0 + sc], &As[sl][2048 + ldso]);
    gl_lds16(&Wm[(size_t)(bcol + srow) * Kstride + k0 + sc],      &Bs[sl][ldso]);
    gl_lds16(&Wm[(size_t)(bcol + 64 + srow) * Kstride + k0 + sc], &Bs[sl][2048 + ldso]);
  };

  stage(0);
  __syncthreads();

  for (int t = 0; t < nt; ++t) {
    if (t + 1 < nt) stage(t + 1);   // issue next-tile loads before compute
    const int sl = t & 1;
    bf16x8 a[4], b[4];
    #pragma unroll
    for (int f = 0; f < 4; ++f) {
      const int ra = wr + f * 16 + (lane & 15);
      a[f] = *(const bf16x8*)&As[sl][ra * 32 + ((lane >> 4) ^ ((ra >> 1) & 3)) * 8];
      const int rb = wc + f * 16 + (lane & 15);
      b[f] = *(const bf16x8*)&Bs[sl][rb * 32 + ((lane >> 4) ^ ((rb >> 1) & 3)) * 8];
    }
    #pragma unroll
    for (int fr = 0; fr < 4; ++fr)
      #pragma unroll
      for (int fc = 0; fc < 4; ++fc)
        acc[fr][fc] = __builtin_amdgcn_mfma_f32_16x16x32_bf16(a[fr], b[fc], acc[fr][fc], 0, 0, 0);
    __syncthreads();   // drains this iter's stage + all waves done with buf[sl]
  }

  const int orow0 = brow + wr + (lane >> 4) * 4;
  const int ocol0 = bcol + wc + (lane & 15);

  if (EPI == 0 && p.vtrans && blockIdx.z == 2) {
    // V projection written transposed: Vt[(b*DM + col)][s], s = row % SEQ
    #pragma unroll
    for (int fr = 0; fr < 4; ++fr) {
      const int row0 = orow0 + fr * 16;
      const int bq = row0 >> 11, s0 = row0 & (SEQ - 1);
      #pragma unroll
      for (int fc = 0; fc < 4; ++fc) {
        const int col = ocol0 + fc * 16;
        const float bvv = bias[col];
        u16x4 o;
        #pragma unroll
        for (int r = 0; r < 4; ++r) o[r] = f2b(acc[fr][fc][r] + bvv);
        *(u16x4*)((u16*)outv + (size_t)(bq * DM + col) * SEQ + s0) = o;
      }
    }
    return;
  }

  const float oscale = (EPI == 0 && p.vtrans && blockIdx.z == 0) ? 0.125f : 1.0f;

  #pragma unroll
  for (int fr = 0; fr < 4; ++fr) {
    #pragma unroll
    for (int fc = 0; fc < 4; ++fc) {
      const int col = ocol0 + fc * 16;
      const float bvv = (EPI == 3) ? 0.0f : bias[col];
      #pragma unroll
      for (int r = 0; r < 4; ++r) {
        const int row = orow0 + fr * 16 + r;
        const size_t idx = (size_t)row * N + col;
        float v = acc[fr][fc][r] + bvv;
        if (EPI == 0) {
          ((u16*)outv)[idx] = f2b(v * oscale);
        } else if (EPI == 1) {
          float ge = 0.5f * v * (1.0f + erff(v * 0.70710678118654752f));
          ((u16*)outv)[idx] = f2b(ge);
        } else if (EPI == 2) {
          ((float*)outv)[idx] = v + resid[idx];
        } else {
          ((float*)outv)[idx] = v;   // partial, bias added in combine
        }
      }
    }
  }
}

// ---------------- flash attention, K-split xN (flash-decoding) -------------
// Grid (SEQ/64, B*NH, NSPLIT): blockIdx.z = key-chunk. Each 2-wave block runs
// the verified 32x32 swapped-QK^T in-register softmax over SEQ/NSPLIT keys,
// writing UNNORMALIZED fp32 partials Op[z] + per-q (m,l). Merge combines.
// x2->x4: R11 showed occupancy 31% (TLP-capped); x4 doubles resident waves
// (LDS 16KB caps at 10 blocks/CU). Defer-max partials merge exactly (each
// Op_i/l_i self-consistent under its own stale max).
__global__ __launch_bounds__(128, 4)
void attn_kernel(const u16* __restrict__ Q, const u16* __restrict__ K,
                 const u16* __restrict__ Vt, float* __restrict__ Opart,
                 float2* __restrict__ ML, int ktps) {
  __shared__ __align__(16) u16 Ks[64 * 64];    // [k][d]
  __shared__ __align__(16) u16 Vts[64 * 64];   // [d][k]
  const int tid = threadIdx.x, lane = tid & 63, w = tid >> 6;
  const int bh = blockIdx.y, b = bh >> 4, h = bh & 15;
  const int kvh = blockIdx.z;
  const int q0 = blockIdx.x * 64 + w * 32;     // wave's q base
  const size_t base = (size_t)b * SEQ * DM + (size_t)h * DH;
  const size_t vbase = (size_t)(b * DM + h * DH) * SEQ;
  float* __restrict__ Op = Opart + (size_t)kvh * MROWS * DM;
  float2* __restrict__ mlp = ML + (size_t)kvh * 2 * NH * SEQ;

  const int l31 = lane & 31, hi = lane >> 5, l7 = l31 & 7;

  // Q fragments (B-operand): col=q=l31, k(d) = dt*16 + hi*8 + j
  bf16x8 qf[4];
  {
    const size_t qrow = base + (size_t)(q0 + l31) * DM;
    #pragma unroll
    for (int dt = 0; dt < 4; ++dt)
      qf[dt] = *(const bf16x8*)&Q[qrow + dt * 16 + hi * 8];
  }

  f32x16 oacc[2] = {};   // d-tiles 0-31, 32-63
  float mq = -1e30f, lq = 0.0f;   // for q = q0 + l31 (column layout)

  for (int kt = kvh * ktps; kt < (kvh + 1) * ktps; ++kt) {
    // stage K[64k][64d] and Vt[64d][64k], swizzled chunk = c ^ (row&7)
    #pragma unroll
    for (int i = 0; i < 4; ++i) {
      const int r0 = w * 32 + i * 8;            // wave-uniform LDS base row
      const int row = r0 + (lane >> 3);
      const int ch = ((lane & 7) ^ (row & 7)) * 8;
      gl_lds16(&K[base + (size_t)(kt * 64 + row) * DM + ch], &Ks[r0 * 64]);
      gl_lds16(&Vt[vbase + (size_t)row * SEQ + kt * 64 + ch], &Vts[r0 * 64]);
    }
    __syncthreads();

    #pragma unroll
    for (int sub = 0; sub < 2; ++sub) {         // 32-key sub-blocks
      // S^T = sum_dt mfma32(Kfrag, Qfrag)
      f32x16 sacc = {};
      __builtin_amdgcn_s_setprio(1);
      #pragma unroll
      for (int dt = 0; dt < 4; ++dt) {
        bf16x8 kf = *(const bf16x8*)&Ks[(sub * 32 + l31) * 64 + (((dt << 1) | hi) ^ l7) * 8];
        sacc = __builtin_amdgcn_mfma_f32_32x32x16_bf16(kf, qf[dt], sacc, 0, 0, 0);
      }
      __builtin_amdgcn_s_setprio(0);

      // column max for q = l31 (16 in-lane + cross-half exchange)
      float tm = sacc[0];
      #pragma unroll
      for (int r = 1; r < 16; ++r) tm = fmaxf(tm, sacc[r]);
      tm = fmaxf(tm, __shfl_xor(tm, 32, 64));

      if (__any(tm > mq + 8.0f)) {
        const float mnew = fmaxf(mq, tm);
        const float fs = __expf(mq - mnew);
        mq = mnew;
        lq *= fs;
        #pragma unroll
        for (int r = 0; r < 16; ++r) {
          const float fsr = __shfl(fs, (r & 3) + 8 * (r >> 2) + 4 * hi, 64);
          oacc[0][r] *= fsr;
          oacc[1][r] *= fsr;
        }
      }

      // exp + pack into PV A-fragments (two k-slots of 16)
      uint32_t wd[2][4];
      float ps = 0.0f;
      #pragma unroll
      for (int half = 0; half < 2; ++half) {
        float p[8];
        #pragma unroll
        for (int j = 0; j < 8; ++j) {
          p[j] = __expf(sacc[half * 8 + j] - mq);
          ps += p[j];
        }
        const uint32_t a = pk2(p[0], p[1]), c = pk2(p[2], p[3]);
        const uint32_t bb = pk2(p[4], p[5]), d = pk2(p[6], p[7]);
        const uint32_t xa = (uint32_t)__shfl_xor((int)a, 32, 64);
        const uint32_t xb = (uint32_t)__shfl_xor((int)bb, 32, 64);
        const uint32_t xc = (uint32_t)__shfl_xor((int)c, 32, 64);
        const uint32_t xd = (uint32_t)__shfl_xor((int)d, 32, 64);
        wd[half][0] = hi ? xb : a;
        wd[half][1] = hi ? xd : c;
        wd[half][2] = hi ? bb : xa;
        wd[half][3] = hi ? d : xc;
      }
      lq += ps;
      bf16x8 pa0, pa1;
      #pragma unroll
      for (int j = 0; j < 4; ++j) {
        ((uint32_t*)&pa0)[j] = wd[0][j];
        ((uint32_t*)&pa1)[j] = wd[1][j];
      }

      // PV: oacc[dt] += pa[ks] * V[ks][dt]
      __builtin_amdgcn_s_setprio(1);
      #pragma unroll
      for (int dt = 0; dt < 2; ++dt) {
        #pragma unroll
        for (int ks = 0; ks < 2; ++ks) {
          bf16x8 vf = *(const bf16x8*)&Vts[(dt * 32 + l31) * 64 +
                                           (((sub << 2) | (ks << 1) | hi) ^ l7) * 8];
          oacc[dt] = __builtin_amdgcn_mfma_f32_32x32x16_bf16(ks ? pa1 : pa0, vf, oacc[dt], 0, 0, 0);
        }
      }
      __builtin_amdgcn_s_setprio(0);
    }
    __syncthreads();
  }

  // write unnormalized partials + (m, l) per q
  const float ltot = lq + __shfl_xor(lq, 32, 64);
  #pragma unroll
  for (int r = 0; r < 16; ++r) {
    const int crow = (r & 3) + 8 * (r >> 2) + 4 * hi;
    const size_t orow = base + (size_t)(q0 + crow) * DM;
    Op[orow + l31]      = oacc[0][r];
    Op[orow + 32 + l31] = oacc[1][r];
  }
  if (hi == 0) mlp[(size_t)bh * SEQ + q0 + l31] = make_float2(mq, ltot);
}

// ---------------- attn merge (2-way) ---------------------------------------
__global__ __launch_bounds__(256)
void attn_merge(const float4* __restrict__ Op0, const float4* __restrict__ Op1,
                const float2* __restrict__ ML, u16* __restrict__ ao) {
  const int row = blockIdx.x, tid = threadIdx.x;
  const int idx4 = row * (DM / 4) + tid;
  const int bh = ((row >> 11) << 4) | (tid >> 4);   // b*16 + h
  const int s = row & (SEQ - 1);
  const float2 a = ML[(size_t)bh * SEQ + s];
  const float2 c = ML[(size_t)(2 * NH) * SEQ + (size_t)bh * SEQ + s];
  const float m = fmaxf(a.x, c.x);
  const float f0 = __expf(a.x - m), f1 = __expf(c.x - m);
  const float inv = 1.0f / (a.y * f0 + c.y * f1);
  const float4 o0 = Op0[idx4], o1 = Op1[idx4];
  u16x4 o;
  o[0] = f2bn((o0.x * f0 + o1.x * f1) * inv);
  o[1] = f2bn((o0.y * f0 + o1.y * f1) * inv);
  o[2] = f2bn((o0.z * f0 + o1.z * f1) * inv);
  o[3] = f2bn((o0.w * f0 + o1.w * f1) * inv);
  ((u16x4*)ao)[idx4] = o;
}

// ---------------- attn merge (4-way) ---------------------------------------
__global__ __launch_bounds__(256)
void attn_merge4(const float* __restrict__ Opart, const float2* __restrict__ ML,
                 u16* __restrict__ ao) {
  const int row = blockIdx.x, tid = threadIdx.x;
  const int idx4 = row * (DM / 4) + tid;
  const int bh = ((row >> 11) << 4) | (tid >> 4);   // b*16 + h
  const int s = row & (SEQ - 1);
  float2 ml[4];
  float m = -1e30f;
  #pragma unroll
  for (int i = 0; i < 4; ++i) {
    ml[i] = ML[(size_t)i * 2 * NH * SEQ + (size_t)bh * SEQ + s];
    m = fmaxf(m, ml[i].x);
  }
  float fw[4], denom = 0.0f;
  #pragma unroll
  for (int i = 0; i < 4; ++i) {
    fw[i] = __expf(ml[i].x - m);
    denom += ml[i].y * fw[i];
  }
  const float inv = 1.0f / denom;
  float4 acc = {0.0f, 0.0f, 0.0f, 0.0f};
  #pragma unroll
  for (int i = 0; i < 4; ++i) {
    const float4 o = ((const float4*)(Opart + (size_t)i * MROWS * DM))[idx4];
    acc.x += o.x * fw[i]; acc.y += o.y * fw[i];
    acc.z += o.z * fw[i]; acc.w += o.w * fw[i];
  }
  u16x4 o;
  o[0] = f2bn(acc.x * inv);
  o[1] = f2bn(acc.y * inv);
  o[2] = f2bn(acc.z * inv);
  o[3] = f2bn(acc.w * inv);
  ((u16x4*)ao)[idx4] = o;
}

// ---------------------------------------------------------------------------
extern "C" void kernel_launch(void* const* d_in, const int* in_sizes, int n_in,
                              void* d_out, int out_size, void* d_ws, size_t ws_size,
                              hipStream_t stream) {
  const float* x    = (const float*)d_in[0];
  const float* Wq   = (const float*)d_in[1];
  const float* bq   = (const float*)d_in[2];
  const float* Wk   = (const float*)d_in[3];
  const float* bk   = (const float*)d_in[4];
  const float* Wv   = (const float*)d_in[5];
  const float* bv   = (const float*)d_in[6];
  const float* Wo   = (const float*)d_in[7];
  const float* bo   = (const float*)d_in[8];
  const float* ln1g = (const float*)d_in[9];
  const float* ln1b = (const float*)d_in[10];
  const float* W1   = (const float*)d_in[11];
  const float* b1   = (const float*)d_in[12];
  const float* W2   = (const float*)d_in[13];
  const float* b2   = (const float*)d_in[14];
  const float* ln2g = (const float*)d_in[15];
  const float* ln2b = (const float*)d_in[16];
  float* out = (float*)d_out;

  char* wsb = (char*)d_ws;
  size_t off = 0;
  auto alloc = [&](size_t bytes) -> char* {
    char* pp = wsb + off;
    off += (bytes + 255) & ~(size_t)255;
    return pp;
  };
  u16* Wq_b = (u16*)alloc((size_t)DM * DM * 2);
  u16* Wk_b = (u16*)alloc((size_t)DM * DM * 2);
  u16* Wv_b = (u16*)alloc((size_t)DM * DM * 2);
  u16* Wo_b = (u16*)alloc((size_t)DM * DM * 2);
  u16* W1_b = (u16*)alloc((size_t)DFF * DM * 2);
  u16* W2_b = (u16*)alloc((size_t)DM * DFF * 2);
  u16* xn   = (u16*)alloc((size_t)MROWS * DM * 2);
  u16* qb   = (u16*)alloc((size_t)MROWS * DM * 2);
  u16* kb   = (u16*)alloc((size_t)MROWS * DM * 2);
  u16* vt   = (u16*)alloc((size_t)MROWS * DM * 2);  // transposed V
  u16* ao   = (u16*)alloc((size_t)MROWS * DM * 2);  // attn out, then LN2 out
  float2* ml = (float2*)alloc((size_t)4 * 2 * NH * SEQ * sizeof(float2));
  // h1, pX, pY allocated consecutively -> contiguous 64 MB for x4 partials
  u16* h1   = (u16*)alloc((size_t)MROWS * DFF * 2); // FFN hidden; attn Op earlier
  float* pX = (float*)alloc((size_t)MROWS * DM * 4);
  float* pY = (float*)alloc((size_t)MROWS * DM * 4);
  const bool ws_x4 = (off <= ws_size);

  // fp32 partial buffers overlaid on dead regions:
  float* pA = (float*)xn;            // xn ∪ qb   (16 MB)
  float* pB = (float*)kb;            // kb ∪ vt   (16 MB)
  float* pC = (float*)h1;            // h1 lower  (16 MB) — dead during O-proj
  float* pD = (float*)((char*)h1 + (size_t)MROWS * DM * 4);  // h1 upper
  float* attnOp = (float*)h1;        // attention partials (up to 64 MB: h1+pX+pY)

  // 1. convert weights to bf16
  CvtArgs ca;
  ca.src[0] = Wq; ca.dst[0] = Wq_b; ca.n4[0] = DM * DM / 4;
  ca.src[1] = Wk; ca.dst[1] = Wk_b; ca.n4[1] = DM * DM / 4;
  ca.src[2] = Wv; ca.dst[2] = Wv_b; ca.n4[2] = DM * DM / 4;
  ca.src[3] = Wo; ca.dst[3] = Wo_b; ca.n4[3] = DM * DM / 4;
  ca.src[4] = W1; ca.dst[4] = W1_b; ca.n4[4] = DFF * DM / 4;
  ca.src[5] = W2; ca.dst[5] = W2_b; ca.n4[5] = DM * DFF / 4;
  cvt_kernel<<<2048, 256, 0, stream>>>(ca);

  // 2. LN1
  ln_kernel<<<MROWS, 256, 0, stream>>>(x, ln1g, ln1b, xn);

  // 3. QKV projections (z-fused; V transposed; Q pre-scaled by 1/8)
  GemmPtrs pq = {};
  pq.W[0] = Wq_b; pq.W[1] = Wk_b; pq.W[2] = Wv_b;
  pq.bias[0] = bq; pq.bias[1] = bk; pq.bias[2] = bv;
  pq.out[0] = qb; pq.out[1] = kb; pq.out[2] = vt;
  pq.vtrans = 1;
  gemm_bt<0><<<dim3(DM / 128, MROWS / 128, 3), 256, 0, stream>>>(xn, pq, MROWS, DM, DM, DM);

  // 4. attention, K-split x4 (x2 fallback) -> fp32 partials + (m,l); merge
  if (ws_x4) {
    attn_kernel<<<dim3(SEQ / 64, 2 * NH, 4), 128, 0, stream>>>(qb, kb, vt, attnOp, ml,
                                                               SEQ / 64 / 4);
    attn_merge4<<<MROWS, 256, 0, stream>>>(attnOp, (const float2*)ml, ao);
  } else {
    attn_kernel<<<dim3(SEQ / 64, 2 * NH, 2), 128, 0, stream>>>(qb, kb, vt, attnOp, ml,
                                                               SEQ / 64 / 2);
    attn_merge<<<MROWS, 256, 0, stream>>>((const float4*)attnOp,
                                          (const float4*)(attnOp + (size_t)MROWS * DM),
                                          (const float2*)ml, ao);
  }

  // 5. output projection, K-split x4 -> partials; fused combine+bias+x+LN2
  GemmPtrs po = {};
  po.W[0] = po.W[1] = po.W[2] = po.W[3] = Wo_b;
  po.bias[0] = po.bias[1] = po.bias[2] = po.bias[3] = bo;
  po.out[0] = pA; po.out[1] = pB; po.out[2] = pC; po.out[3] = pD;
  gemm_bt<3><<<dim3(DM / 128, MROWS / 128, 4), 256, 0, stream>>>(ao, po, MROWS, DM, DM, DM / 4);
  combine4_ln_kernel<<<MROWS, 256, 0, stream>>>((const float4*)pA, (const float4*)pB,
                                                (const float4*)pC, (const float4*)pD,
                                                (const float4*)bo, (const float4*)x,
                                                (float4*)out, ln2g, ln2b, ao);

  // 6. FFN up + GELU (input: LN2 output in ao; h1 now free for FFN hidden)
  GemmPtrs p1 = {};
  p1.W[0] = W1_b; p1.bias[0] = b1; p1.out[0] = h1;
  gemm_bt<1><<<dim3(DFF / 128, MROWS / 128, 1), 256, 0, stream>>>(ao, p1, MROWS, DFF, DM, DM);

  // 7. FFN down, K-split (x4 if ws allows, else x2) -> partials -> combine
  if (ws_x4) {
    GemmPtrs p2 = {};
    p2.W[0] = p2.W[1] = p2.W[2] = p2.W[3] = W2_b;
    p2.bias[0] = p2.bias[1] = p2.bias[2] = p2.bias[3] = b2;
    p2.out[0] = pA; p2.out[1] = pB; p2.out[2] = pX; p2.out[3] = pY;
    gemm_bt<3><<<dim3(DM / 128, MROWS / 128, 4), 256, 0, stream>>>(h1, p2, MROWS, DM, DFF, DFF / 4);
    combine4_kernel<<<2048, 256, 0, stream>>>((const float4*)pA, (const float4*)pB,
                                              (const float4*)pX, (const float4*)pY,
                                              (const float4*)b2, (const float4*)out,
                                              (float4*)out, MROWS * DM / 4, DM / 4 - 1);
  } else {
    GemmPtrs p2 = {};
    p2.W[0] = p2.W[1] = W2_b;
    p2.bias[0] = p2.bias[1] = b2;
    p2.out[0] = pA; p2.out[1] = pB;
    gemm_bt<3><<<dim3(DM / 128, MROWS / 128, 2), 256, 0, stream>>>(h1, p2, MROWS, DM, DFF, DFF / 2);
    combine_kernel<<<2048, 256, 0, stream>>>((const float4*)pA, (const float4*)pB,
                                             (const float4*)b2, (const float4*)out,
                                             (float4*)out, MROWS * DM / 4, DM / 4 - 1);
  }
}

// Round 14
// 300.170 us; speedup vs baseline: 1.0014x; 1.0014x over previous
//
#include <hip/hip_runtime.h>
#include <hip/hip_bf16.h>
#include <stdint.h>

#define DM 1024
#define DFF 4096
#define NH 16
#define DH 64
#define SEQ 2048
#define MROWS 4096  // B*S

typedef unsigned short u16;
typedef __attribute__((ext_vector_type(8))) short bf16x8;
typedef __attribute__((ext_vector_type(4))) float f32x4;
typedef __attribute__((ext_vector_type(16))) float f32x16;
typedef __attribute__((ext_vector_type(4))) unsigned short u16x4;

__device__ __forceinline__ u16 f2b(float f) {
  union { float f; uint32_t u; } v; v.f = f;
  uint32_t r = v.u + 0x7FFFu + ((v.u >> 16) & 1u);
  return (u16)(r >> 16);
}

// native convert — clang emits v_cvt_pk_bf16_f32 for pairs (RNE)
__device__ __forceinline__ u16 f2bn(float f) {
  __hip_bfloat16 h = __float2bfloat16(f);
  return *reinterpret_cast<u16*>(&h);
}

__device__ __forceinline__ uint32_t pk2(float lo, float hi) {
  return (uint32_t)f2bn(lo) | ((uint32_t)f2bn(hi) << 16);
}

__device__ __forceinline__ void gl_lds16(const void* g, void* l) {
  __builtin_amdgcn_global_load_lds(
      (const __attribute__((address_space(1))) uint32_t*)g,
      (__attribute__((address_space(3))) uint32_t*)l, 16, 0, 0);
}

// ---------------- weight fp32 -> bf16 convert (all 6 weights, one kernel) --
struct CvtArgs { const float* src[6]; u16* dst[6]; int n4[6]; };

__global__ void cvt_kernel(CvtArgs a) {
  const int stride = gridDim.x * blockDim.x;
  const int t0 = blockIdx.x * blockDim.x + threadIdx.x;
  for (int i = 0; i < 6; ++i) {
    const float4* s = (const float4*)a.src[i];
    u16x4* d = (u16x4*)a.dst[i];
    const int n = a.n4[i];
    for (int idx = t0; idx < n; idx += stride) {
      float4 v = s[idx];
      u16x4 o;
      o[0] = f2b(v.x); o[1] = f2b(v.y); o[2] = f2b(v.z); o[3] = f2b(v.w);
      d[idx] = o;
    }
  }
}

// ---------------- fused LayerNorm: fp32 in -> bf16 out ---------------------
__global__ __launch_bounds__(256)
void ln_kernel(const float* __restrict__ x, const float* __restrict__ g,
               const float* __restrict__ be, u16* __restrict__ out) {
  const int row = blockIdx.x;
  const int tid = threadIdx.x;
  const float4 v = ((const float4*)(x + (size_t)row * DM))[tid];
  float s  = v.x + v.y + v.z + v.w;
  float s2 = v.x * v.x + v.y * v.y + v.z * v.z + v.w * v.w;
  #pragma unroll
  for (int m = 1; m < 64; m <<= 1) {
    s  += __shfl_xor(s,  m, 64);
    s2 += __shfl_xor(s2, m, 64);
  }
  __shared__ float red[8];
  const int w = tid >> 6, lane = tid & 63;
  if (lane == 0) { red[w] = s; red[4 + w] = s2; }
  __syncthreads();
  s  = red[0] + red[1] + red[2] + red[3];
  s2 = red[4] + red[5] + red[6] + red[7];
  const float mu  = s * (1.0f / DM);
  const float var = s2 * (1.0f / DM) - mu * mu;
  const float rstd = rsqrtf(var + 1e-5f);
  const float4 gv = ((const float4*)g)[tid];
  const float4 bv = ((const float4*)be)[tid];
  u16x4 o;
  o[0] = f2b((v.x - mu) * rstd * gv.x + bv.x);
  o[1] = f2b((v.y - mu) * rstd * gv.y + bv.y);
  o[2] = f2b((v.z - mu) * rstd * gv.z + bv.z);
  o[3] = f2b((v.w - mu) * rstd * gv.w + bv.w);
  ((u16x4*)(out + (size_t)row * DM))[tid] = o;
}

// ---------------- combine (2-way): out = p0 + p1 + bias + resid (fp32) -----
__global__ __launch_bounds__(256)
void combine_kernel(const float4* __restrict__ p0, const float4* __restrict__ p1,
                    const float4* __restrict__ bias, const float4* __restrict__ resid,
                    float4* __restrict__ out, int total4, int colmask4) {
  for (int i = blockIdx.x * 256 + threadIdx.x; i < total4; i += gridDim.x * 256) {
    float4 a = p0[i], b = p1[i], bs = bias[i & colmask4], rr = resid[i];
    float4 o;
    o.x = a.x + b.x + bs.x + rr.x;
    o.y = a.y + b.y + bs.y + rr.y;
    o.z = a.z + b.z + bs.z + rr.z;
    o.w = a.w + b.w + bs.w + rr.w;
    out[i] = o;
  }
}

// ---------------- combine (4-way): out = Σp + bias + resid (fp32) ----------
__global__ __launch_bounds__(256)
void combine4_kernel(const float4* __restrict__ p0, const float4* __restrict__ p1,
                     const float4* __restrict__ p2, const float4* __restrict__ p3,
                     const float4* __restrict__ bias, const float4* __restrict__ resid,
                     float4* __restrict__ out, int total4, int colmask4) {
  for (int i = blockIdx.x * 256 + threadIdx.x; i < total4; i += gridDim.x * 256) {
    float4 a = p0[i], b = p1[i], c = p2[i], d = p3[i];
    float4 bs = bias[i & colmask4], rr = resid[i];
    float4 o;
    o.x = (a.x + b.x) + (c.x + d.x) + bs.x + rr.x;
    o.y = (a.y + b.y) + (c.y + d.y) + bs.y + rr.y;
    o.z = (a.z + b.z) + (c.z + d.z) + bs.z + rr.z;
    o.w = (a.w + b.w) + (c.w + d.w) + bs.w + rr.w;
    out[i] = o;
  }
}

// ------- fused 4-way combine + LayerNorm: x1 = Σp+bias+resid (fp32 out),
//         norm = LN(x1)*g+b (bf16 out, separate buffer) ---------------------
__global__ __launch_bounds__(256)
void combine4_ln_kernel(const float4* __restrict__ p0, const float4* __restrict__ p1,
                        const float4* __restrict__ p2, const float4* __restrict__ p3,
                        const float4* __restrict__ bias, const float4* __restrict__ resid,
                        float4* __restrict__ xout,
                        const float* __restrict__ g, const float* __restrict__ be,
                        u16* __restrict__ nout) {
  const int row = blockIdx.x;
  const int tid = threadIdx.x;
  const int i = row * (DM / 4) + tid;
  const float4 a = p0[i], b = p1[i], c = p2[i], d = p3[i];
  const float4 bs = bias[tid], rr = resid[i];
  float4 v;
  v.x = (a.x + b.x) + (c.x + d.x) + bs.x + rr.x;
  v.y = (a.y + b.y) + (c.y + d.y) + bs.y + rr.y;
  v.z = (a.z + b.z) + (c.z + d.z) + bs.z + rr.z;
  v.w = (a.w + b.w) + (c.w + d.w) + bs.w + rr.w;
  xout[i] = v;
  float s  = v.x + v.y + v.z + v.w;
  float s2 = v.x * v.x + v.y * v.y + v.z * v.z + v.w * v.w;
  #pragma unroll
  for (int m = 1; m < 64; m <<= 1) {
    s  += __shfl_xor(s,  m, 64);
    s2 += __shfl_xor(s2, m, 64);
  }
  __shared__ float red[8];
  const int w = tid >> 6, lane = tid & 63;
  if (lane == 0) { red[w] = s; red[4 + w] = s2; }
  __syncthreads();
  s  = red[0] + red[1] + red[2] + red[3];
  s2 = red[4] + red[5] + red[6] + red[7];
  const float mu  = s * (1.0f / DM);
  const float var = s2 * (1.0f / DM) - mu * mu;
  const float rstd = rsqrtf(var + 1e-5f);
  const float4 gv = ((const float4*)g)[tid];
  const float4 bv = ((const float4*)be)[tid];
  u16x4 o;
  o[0] = f2b((v.x - mu) * rstd * gv.x + bv.x);
  o[1] = f2b((v.y - mu) * rstd * gv.y + bv.y);
  o[2] = f2b((v.z - mu) * rstd * gv.z + bv.z);
  o[3] = f2b((v.w - mu) * rstd * gv.w + bv.w);
  ((u16x4*)(nout + (size_t)row * DM))[tid] = o;
}

// ---------------- GEMM: C[M,N] = A[M,K](bf16) * W[N,K](bf16)^T + bias ------
// 2-phase double-buffer at BK=32 (guide's verified minimum T3 recipe).
// __launch_bounds__(256,4): total VGPR+AGPR <= 128/wave (unified file).
// LDS swizzle chunk ^= (row>>1)&3 (2-way = free, m136), both-sides (rule #21).
// EPI 0 z==0 + vtrans: Q scaled by 0.125*log2(e) — head-dim scale AND the
// exp->exp2 domain change folded into the projection (cancels in softmax).
struct GemmPtrs { const u16* W[4]; const float* bias[4]; void* out[4];
                  const float* resid; int vtrans; };

template<int EPI>
__global__ __launch_bounds__(256, 4)
void gemm_bt(const u16* __restrict__ A, GemmPtrs p, int M, int N,
             int Kstride, int Kchunk) {
  __shared__ __align__(16) u16 As[2][128 * 32];
  __shared__ __align__(16) u16 Bs[2][128 * 32];
  const u16* __restrict__ Wm = p.W[blockIdx.z];
  const float* __restrict__ bias = p.bias[blockIdx.z];
  void* outv = p.out[blockIdx.z];
  const float* resid = p.resid;

  const int tid = threadIdx.x;
  const int lane = tid & 63;
  const int w = tid >> 6;
  const int brow = blockIdx.y * 128;
  const int bcol = blockIdx.x * 128;
  const int wr = (w >> 1) * 64, wc = (w & 1) * 64;
  const int koff = (EPI == 3) ? blockIdx.z * Kchunk : 0;

  f32x4 acc[4][4] = {};

  const int srow = tid >> 2;
  const int sc = ((tid & 3) ^ ((tid >> 3) & 3)) * 8;   // elements
  const int ldso = w * 512;                            // u16; +2048 for rows 64+

  const int nt = Kchunk >> 5;

  auto stage = [&](int t) {
    const int sl = t & 1;
    const int k0 = koff + t * 32;
    gl_lds16(&A [(size_t)(brow + srow) * Kstride + k0 + sc],      &As[sl][ldso]);
    gl_lds16(&A [(size_t)(brow + 64 + srow) * Kstride + k0 + sc], &As[sl][2048 + ldso]);
    gl_lds16(&Wm[(size_t)(bcol + srow) * Kstride + k0 + sc],      &Bs[sl][ldso]);
    gl_lds16(&Wm[(size_t)(bcol + 64 + srow) * Kstride + k0 + sc], &Bs[sl][2048 + ldso]);
  };

  stage(0);
  __syncthreads();

  for (int t = 0; t < nt; ++t) {
    if (t + 1 < nt) stage(t + 1);   // issue next-tile loads before compute
    const int sl = t & 1;
    bf16x8 a[4], b[4];
    #pragma unroll
    for (int f = 0; f < 4; ++f) {
      const int ra = wr + f * 16 + (lane & 15);
      a[f] = *(const bf16x8*)&As[sl][ra * 32 + ((lane >> 4) ^ ((ra >> 1) & 3)) * 8];
      const int rb = wc + f * 16 + (lane & 15);
      b[f] = *(const bf16x8*)&Bs[sl][rb * 32 + ((lane >> 4) ^ ((rb >> 1) & 3)) * 8];
    }
    #pragma unroll
    for (int fr = 0; fr < 4; ++fr)
      #pragma unroll
      for (int fc = 0; fc < 4; ++fc)
        acc[fr][fc] = __builtin_amdgcn_mfma_f32_16x16x32_bf16(a[fr], b[fc], acc[fr][fc], 0, 0, 0);
    __syncthreads();   // drains this iter's stage + all waves done with buf[sl]
  }

  const int orow0 = brow + wr + (lane >> 4) * 4;
  const int ocol0 = bcol + wc + (lane & 15);

  if (EPI == 0 && p.vtrans && blockIdx.z == 2) {
    // V projection written transposed: Vt[(b*DM + col)][s], s = row % SEQ
    #pragma unroll
    for (int fr = 0; fr < 4; ++fr) {
      const int row0 = orow0 + fr * 16;
      const int bq = row0 >> 11, s0 = row0 & (SEQ - 1);
      #pragma unroll
      for (int fc = 0; fc < 4; ++fc) {
        const int col = ocol0 + fc * 16;
        const float bvv = bias[col];
        u16x4 o;
        #pragma unroll
        for (int r = 0; r < 4; ++r) o[r] = f2b(acc[fr][fc][r] + bvv);
        *(u16x4*)((u16*)outv + (size_t)(bq * DM + col) * SEQ + s0) = o;
      }
    }
    return;
  }

  // 0.125 (1/sqrt(64)) * log2(e) — see attn (exp2-domain softmax)
  const float oscale = (EPI == 0 && p.vtrans && blockIdx.z == 0) ? 0.18033688011112042f : 1.0f;

  #pragma unroll
  for (int fr = 0; fr < 4; ++fr) {
    #pragma unroll
    for (int fc = 0; fc < 4; ++fc) {
      const int col = ocol0 + fc * 16;
      const float bvv = (EPI == 3) ? 0.0f : bias[col];
      #pragma unroll
      for (int r = 0; r < 4; ++r) {
        const int row = orow0 + fr * 16 + r;
        const size_t idx = (size_t)row * N + col;
        float v = acc[fr][fc][r] + bvv;
        if (EPI == 0) {
          ((u16*)outv)[idx] = f2b(v * oscale);
        } else if (EPI == 1) {
          float ge = 0.5f * v * (1.0f + erff(v * 0.70710678118654752f));
          ((u16*)outv)[idx] = f2b(ge);
        } else if (EPI == 2) {
          ((float*)outv)[idx] = v + resid[idx];
        } else {
          ((float*)outv)[idx] = v;   // partial, bias added in combine
        }
      }
    }
  }
}

// ---------------- flash attention, K-split x2 (flash-decoding) -------------
// Grid (SEQ/64, B*NH, 2). R12's x4 regressed (doubled partial HBM traffic,
// no occupancy gain) — x2 is the measured optimum. Scores arrive in the
// LOG2 domain (Q pre-scaled by 0.125*log2e), so softmax uses native exp2f
// (v_exp_f32, no mul). THR 8 nats = 11.5 log2-units. Max/sum reductions are
// pairwise trees (depth 4, static indexing).
__global__ __launch_bounds__(128, 4)
void attn_kernel(const u16* __restrict__ Q, const u16* __restrict__ K,
                 const u16* __restrict__ Vt, float* __restrict__ Opart,
                 float2* __restrict__ ML, int ktps) {
  __shared__ __align__(16) u16 Ks[64 * 64];    // [k][d]
  __shared__ __align__(16) u16 Vts[64 * 64];   // [d][k]
  const int tid = threadIdx.x, lane = tid & 63, w = tid >> 6;
  const int bh = blockIdx.y, b = bh >> 4, h = bh & 15;
  const int kvh = blockIdx.z;
  const int q0 = blockIdx.x * 64 + w * 32;     // wave's q base
  const size_t base = (size_t)b * SEQ * DM + (size_t)h * DH;
  const size_t vbase = (size_t)(b * DM + h * DH) * SEQ;
  float* __restrict__ Op = Opart + (size_t)kvh * MROWS * DM;
  float2* __restrict__ mlp = ML + (size_t)kvh * 2 * NH * SEQ;

  const int l31 = lane & 31, hi = lane >> 5, l7 = l31 & 7;

  // Q fragments (B-operand): col=q=l31, k(d) = dt*16 + hi*8 + j
  bf16x8 qf[4];
  {
    const size_t qrow = base + (size_t)(q0 + l31) * DM;
    #pragma unroll
    for (int dt = 0; dt < 4; ++dt)
      qf[dt] = *(const bf16x8*)&Q[qrow + dt * 16 + hi * 8];
  }

  f32x16 oacc[2] = {};   // d-tiles 0-31, 32-63
  float mq = -1e30f, lq = 0.0f;   // for q = q0 + l31 (column layout)

  for (int kt = kvh * ktps; kt < (kvh + 1) * ktps; ++kt) {
    // stage K[64k][64d] and Vt[64d][64k], swizzled chunk = c ^ (row&7)
    #pragma unroll
    for (int i = 0; i < 4; ++i) {
      const int r0 = w * 32 + i * 8;            // wave-uniform LDS base row
      const int row = r0 + (lane >> 3);
      const int ch = ((lane & 7) ^ (row & 7)) * 8;
      gl_lds16(&K[base + (size_t)(kt * 64 + row) * DM + ch], &Ks[r0 * 64]);
      gl_lds16(&Vt[vbase + (size_t)row * SEQ + kt * 64 + ch], &Vts[r0 * 64]);
    }
    __syncthreads();

    #pragma unroll
    for (int sub = 0; sub < 2; ++sub) {         // 32-key sub-blocks
      // S^T (log2 domain) = sum_dt mfma32(Kfrag, Qfrag)
      f32x16 sacc = {};
      __builtin_amdgcn_s_setprio(1);
      #pragma unroll
      for (int dt = 0; dt < 4; ++dt) {
        bf16x8 kf = *(const bf16x8*)&Ks[(sub * 32 + l31) * 64 + (((dt << 1) | hi) ^ l7) * 8];
        sacc = __builtin_amdgcn_mfma_f32_32x32x16_bf16(kf, qf[dt], sacc, 0, 0, 0);
      }
      __builtin_amdgcn_s_setprio(0);

      // column max for q = l31: pairwise tree (depth 4) + cross-half exchange
      float tv[8];
      #pragma unroll
      for (int r = 0; r < 8; ++r) tv[r] = fmaxf(sacc[r], sacc[r + 8]);
      #pragma unroll
      for (int r = 0; r < 4; ++r) tv[r] = fmaxf(tv[r], tv[r + 4]);
      float tm = fmaxf(fmaxf(tv[0], tv[1]), fmaxf(tv[2], tv[3]));
      tm = fmaxf(tm, __shfl_xor(tm, 32, 64));

      if (__any(tm > mq + 11.5f)) {
        const float mnew = fmaxf(mq, tm);
        const float fs = exp2f(mq - mnew);
        mq = mnew;
        lq *= fs;
        #pragma unroll
        for (int r = 0; r < 16; ++r) {
          const float fsr = __shfl(fs, (r & 3) + 8 * (r >> 2) + 4 * hi, 64);
          oacc[0][r] *= fsr;
          oacc[1][r] *= fsr;
        }
      }

      // exp2 + pack into PV A-fragments (two k-slots of 16)
      uint32_t wd[2][4];
      float pall[16];
      #pragma unroll
      for (int half = 0; half < 2; ++half) {
        float p[8];
        #pragma unroll
        for (int j = 0; j < 8; ++j) {
          p[j] = exp2f(sacc[half * 8 + j] - mq);
          pall[half * 8 + j] = p[j];
        }
        const uint32_t a = pk2(p[0], p[1]), c = pk2(p[2], p[3]);
        const uint32_t bb = pk2(p[4], p[5]), d = pk2(p[6], p[7]);
        const uint32_t xa = (uint32_t)__shfl_xor((int)a, 32, 64);
        const uint32_t xb = (uint32_t)__shfl_xor((int)bb, 32, 64);
        const uint32_t xc = (uint32_t)__shfl_xor((int)c, 32, 64);
        const uint32_t xd = (uint32_t)__shfl_xor((int)d, 32, 64);
        wd[half][0] = hi ? xb : a;
        wd[half][1] = hi ? xd : c;
        wd[half][2] = hi ? bb : xa;
        wd[half][3] = hi ? d : xc;
      }
      // pairwise-tree sum of the 16 p's
      #pragma unroll
      for (int r = 0; r < 8; ++r) pall[r] += pall[r + 8];
      #pragma unroll
      for (int r = 0; r < 4; ++r) pall[r] += pall[r + 4];
      lq += (pall[0] + pall[1]) + (pall[2] + pall[3]);

      bf16x8 pa0, pa1;
      #pragma unroll
      for (int j = 0; j < 4; ++j) {
        ((uint32_t*)&pa0)[j] = wd[0][j];
        ((uint32_t*)&pa1)[j] = wd[1][j];
      }

      // PV: oacc[dt] += pa[ks] * V[ks][dt]
      __builtin_amdgcn_s_setprio(1);
      #pragma unroll
      for (int dt = 0; dt < 2; ++dt) {
        #pragma unroll
        for (int ks = 0; ks < 2; ++ks) {
          bf16x8 vf = *(const bf16x8*)&Vts[(dt * 32 + l31) * 64 +
                                           (((sub << 2) | (ks << 1) | hi) ^ l7) * 8];
          oacc[dt] = __builtin_amdgcn_mfma_f32_32x32x16_bf16(ks ? pa1 : pa0, vf, oacc[dt], 0, 0, 0);
        }
      }
      __builtin_amdgcn_s_setprio(0);
    }
    __syncthreads();
  }

  // write unnormalized partials + (m, l) per q  (m in log2 domain)
  const float ltot = lq + __shfl_xor(lq, 32, 64);
  #pragma unroll
  for (int r = 0; r < 16; ++r) {
    const int crow = (r & 3) + 8 * (r >> 2) + 4 * hi;
    const size_t orow = base + (size_t)(q0 + crow) * DM;
    Op[orow + l31]      = oacc[0][r];
    Op[orow + 32 + l31] = oacc[1][r];
  }
  if (hi == 0) mlp[(size_t)bh * SEQ + q0 + l31] = make_float2(mq, ltot);
}

// ---------------- attn merge (2-way, log2-domain m) -------------------------
__global__ __launch_bounds__(256)
void attn_merge(const float4* __restrict__ Op0, const float4* __restrict__ Op1,
                const float2* __restrict__ ML, u16* __restrict__ ao) {
  const int row = blockIdx.x, tid = threadIdx.x;
  const int idx4 = row * (DM / 4) + tid;
  const int bh = ((row >> 11) << 4) | (tid >> 4);   // b*16 + h
  const int s = row & (SEQ - 1);
  const float2 a = ML[(size_t)bh * SEQ + s];
  const float2 c = ML[(size_t)(2 * NH) * SEQ + (size_t)bh * SEQ + s];
  const float m = fmaxf(a.x, c.x);
  const float f0 = exp2f(a.x - m), f1 = exp2f(c.x - m);
  const float inv = 1.0f / (a.y * f0 + c.y * f1);
  const float4 o0 = Op0[idx4], o1 = Op1[idx4];
  u16x4 o;
  o[0] = f2bn((o0.x * f0 + o1.x * f1) * inv);
  o[1] = f2bn((o0.y * f0 + o1.y * f1) * inv);
  o[2] = f2bn((o0.z * f0 + o1.z * f1) * inv);
  o[3] = f2bn((o0.w * f0 + o1.w * f1) * inv);
  ((u16x4*)ao)[idx4] = o;
}

// ---------------------------------------------------------------------------
extern "C" void kernel_launch(void* const* d_in, const int* in_sizes, int n_in,
                              void* d_out, int out_size, void* d_ws, size_t ws_size,
                              hipStream_t stream) {
  const float* x    = (const float*)d_in[0];
  const float* Wq   = (const float*)d_in[1];
  const float* bq   = (const float*)d_in[2];
  const float* Wk   = (const float*)d_in[3];
  const float* bk   = (const float*)d_in[4];
  const float* Wv   = (const float*)d_in[5];
  const float* bv   = (const float*)d_in[6];
  const float* Wo   = (const float*)d_in[7];
  const float* bo   = (const float*)d_in[8];
  const float* ln1g = (const float*)d_in[9];
  const float* ln1b = (const float*)d_in[10];
  const float* W1   = (const float*)d_in[11];
  const float* b1   = (const float*)d_in[12];
  const float* W2   = (const float*)d_in[13];
  const float* b2   = (const float*)d_in[14];
  const float* ln2g = (const float*)d_in[15];
  const float* ln2b = (const float*)d_in[16];
  float* out = (float*)d_out;

  char* wsb = (char*)d_ws;
  size_t off = 0;
  auto alloc = [&](size_t bytes) -> char* {
    char* pp = wsb + off;
    off += (bytes + 255) & ~(size_t)255;
    return pp;
  };
  u16* Wq_b = (u16*)alloc((size_t)DM * DM * 2);
  u16* Wk_b = (u16*)alloc((size_t)DM * DM * 2);
  u16* Wv_b = (u16*)alloc((size_t)DM * DM * 2);
  u16* Wo_b = (u16*)alloc((size_t)DM * DM * 2);
  u16* W1_b = (u16*)alloc((size_t)DFF * DM * 2);
  u16* W2_b = (u16*)alloc((size_t)DM * DFF * 2);
  u16* xn   = (u16*)alloc((size_t)MROWS * DM * 2);
  u16* qb   = (u16*)alloc((size_t)MROWS * DM * 2);
  u16* kb   = (u16*)alloc((size_t)MROWS * DM * 2);
  u16* vt   = (u16*)alloc((size_t)MROWS * DM * 2);  // transposed V
  u16* ao   = (u16*)alloc((size_t)MROWS * DM * 2);  // attn out, then LN2 out
  float2* ml = (float2*)alloc((size_t)2 * 2 * NH * SEQ * sizeof(float2));
  u16* h1   = (u16*)alloc((size_t)MROWS * DFF * 2); // FFN hidden; attn Op earlier
  float* pX = (float*)alloc((size_t)MROWS * DM * 4);
  float* pY = (float*)alloc((size_t)MROWS * DM * 4);
  const bool ws_x4 = (off <= ws_size);

  // fp32 partial buffers overlaid on dead regions:
  float* pA = (float*)xn;            // xn ∪ qb   (16 MB)
  float* pB = (float*)kb;            // kb ∪ vt   (16 MB)
  float* pC = (float*)h1;            // h1 lower  (16 MB) — dead during O-proj
  float* pD = (float*)((char*)h1 + (size_t)MROWS * DM * 4);  // h1 upper
  float* attnOp = (float*)h1;        // attention x2 partials (32 MB = h1)

  // 1. convert weights to bf16
  CvtArgs ca;
  ca.src[0] = Wq; ca.dst[0] = Wq_b; ca.n4[0] = DM * DM / 4;
  ca.src[1] = Wk; ca.dst[1] = Wk_b; ca.n4[1] = DM * DM / 4;
  ca.src[2] = Wv; ca.dst[2] = Wv_b; ca.n4[2] = DM * DM / 4;
  ca.src[3] = Wo; ca.dst[3] = Wo_b; ca.n4[3] = DM * DM / 4;
  ca.src[4] = W1; ca.dst[4] = W1_b; ca.n4[4] = DFF * DM / 4;
  ca.src[5] = W2; ca.dst[5] = W2_b; ca.n4[5] = DM * DFF / 4;
  cvt_kernel<<<2048, 256, 0, stream>>>(ca);

  // 2. LN1
  ln_kernel<<<MROWS, 256, 0, stream>>>(x, ln1g, ln1b, xn);

  // 3. QKV projections (z-fused; V transposed; Q pre-scaled 0.125*log2e)
  GemmPtrs pq = {};
  pq.W[0] = Wq_b; pq.W[1] = Wk_b; pq.W[2] = Wv_b;
  pq.bias[0] = bq; pq.bias[1] = bk; pq.bias[2] = bv;
  pq.out[0] = qb; pq.out[1] = kb; pq.out[2] = vt;
  pq.vtrans = 1;
  gemm_bt<0><<<dim3(DM / 128, MROWS / 128, 3), 256, 0, stream>>>(xn, pq, MROWS, DM, DM, DM);

  // 4. attention, K-split x2 -> fp32 partials + (m,l); merge -> ao (bf16)
  attn_kernel<<<dim3(SEQ / 64, 2 * NH, 2), 128, 0, stream>>>(qb, kb, vt, attnOp, ml,
                                                             SEQ / 64 / 2);
  attn_merge<<<MROWS, 256, 0, stream>>>((const float4*)attnOp,
                                        (const float4*)(attnOp + (size_t)MROWS * DM),
                                        (const float2*)ml, ao);

  // 5. output projection, K-split x4 -> partials; fused combine+bias+x+LN2
  GemmPtrs po = {};
  po.W[0] = po.W[1] = po.W[2] = po.W[3] = Wo_b;
  po.bias[0] = po.bias[1] = po.bias[2] = po.bias[3] = bo;
  po.out[0] = pA; po.out[1] = pB; po.out[2] = pC; po.out[3] = pD;
  gemm_bt<3><<<dim3(DM / 128, MROWS / 128, 4), 256, 0, stream>>>(ao, po, MROWS, DM, DM, DM / 4);
  combine4_ln_kernel<<<MROWS, 256, 0, stream>>>((const float4*)pA, (const float4*)pB,
                                                (const float4*)pC, (const float4*)pD,
                                                (const float4*)bo, (const float4*)x,
                                                (float4*)out, ln2g, ln2b, ao);

  // 6. FFN up + GELU (input: LN2 output in ao; h1 now free for FFN hidden)
  GemmPtrs p1 = {};
  p1.W[0] = W1_b; p1.bias[0] = b1; p1.out[0] = h1;
  gemm_bt<1><<<dim3(DFF / 128, MROWS / 128, 1), 256, 0, stream>>>(ao, p1, MROWS, DFF, DM, DM);

  // 7. FFN down, K-split (x4 if ws allows, else x2) -> partials -> combine
  if (ws_x4) {
    GemmPtrs p2 = {};
    p2.W[0] = p2.W[1] = p2.W[2] = p2.W[3] = W2_b;
    p2.bias[0] = p2.bias[1] = p2.bias[2] = p2.bias[3] = b2;
    p2.out[0] = pA; p2.out[1] = pB; p2.out[2] = pX; p2.out[3] = pY;
    gemm_bt<3><<<dim3(DM / 128, MROWS / 128, 4), 256, 0, stream>>>(h1, p2, MROWS, DM, DFF, DFF / 4);
    combine4_kernel<<<2048, 256, 0, stream>>>((const float4*)pA, (const float4*)pB,
                                              (const float4*)pX, (const float4*)pY,
                                              (const float4*)b2, (const float4*)out,
                                              (float4*)out, MROWS * DM / 4, DM / 4 - 1);
  } else {
    GemmPtrs p2 = {};
    p2.W[0] = p2.W[1] = W2_b;
    p2.bias[0] = p2.bias[1] = b2;
    p2.out[0] = pA; p2.out[1] = pB;
    gemm_bt<3><<<dim3(DM / 128, MROWS / 128, 2), 256, 0, stream>>>(h1, p2, MROWS, DM, DFF, DFF / 2);
    combine_kernel<<<2048, 256, 0, stream>>>((const float4*)pA, (const float4*)pB,
                                             (const float4*)b2, (const float4*)out,
                                             (float4*)out, MROWS * DM / 4, DM / 4 - 1);
  }
}

// Round 15
// 287.191 us; speedup vs baseline: 1.0467x; 1.0452x over previous
//
#include <hip/hip_runtime.h>
#include <hip/hip_bf16.h>
#include <stdint.h>

#define DM 1024
#define DFF 4096
#define NH 16
#define DH 64
#define SEQ 2048
#define MROWS 4096  // B*S

typedef unsigned short u16;
typedef __attribute__((ext_vector_type(8))) short bf16x8;
typedef __attribute__((ext_vector_type(4))) float f32x4;
typedef __attribute__((ext_vector_type(16))) float f32x16;
typedef __attribute__((ext_vector_type(4))) unsigned short u16x4;

__device__ __forceinline__ u16 f2b(float f) {
  union { float f; uint32_t u; } v; v.f = f;
  uint32_t r = v.u + 0x7FFFu + ((v.u >> 16) & 1u);
  return (u16)(r >> 16);
}

// native convert — clang emits v_cvt_pk_bf16_f32 for pairs (RNE)
__device__ __forceinline__ u16 f2bn(float f) {
  __hip_bfloat16 h = __float2bfloat16(f);
  return *reinterpret_cast<u16*>(&h);
}

__device__ __forceinline__ uint32_t pk2(float lo, float hi) {
  return (uint32_t)f2bn(lo) | ((uint32_t)f2bn(hi) << 16);
}

// bare v_exp_f32 (2^x) — no OCML wrapper (plain exp2f lowers to the precise
// OCML path and cost MORE VALU than __expf in R13)
__device__ __forceinline__ float ex2(float x) {
  return __builtin_amdgcn_exp2f(x);
}

__device__ __forceinline__ void gl_lds16(const void* g, void* l) {
  __builtin_amdgcn_global_load_lds(
      (const __attribute__((address_space(1))) uint32_t*)g,
      (__attribute__((address_space(3))) uint32_t*)l, 16, 0, 0);
}

// ---------------- weight fp32 -> bf16 convert (all 6 weights, one kernel) --
struct CvtArgs { const float* src[6]; u16* dst[6]; int n4[6]; };

__global__ void cvt_kernel(CvtArgs a) {
  const int stride = gridDim.x * blockDim.x;
  const int t0 = blockIdx.x * blockDim.x + threadIdx.x;
  for (int i = 0; i < 6; ++i) {
    const float4* s = (const float4*)a.src[i];
    u16x4* d = (u16x4*)a.dst[i];
    const int n = a.n4[i];
    for (int idx = t0; idx < n; idx += stride) {
      float4 v = s[idx];
      u16x4 o;
      o[0] = f2b(v.x); o[1] = f2b(v.y); o[2] = f2b(v.z); o[3] = f2b(v.w);
      d[idx] = o;
    }
  }
}

// ---------------- fused LayerNorm: fp32 in -> bf16 out ---------------------
__global__ __launch_bounds__(256)
void ln_kernel(const float* __restrict__ x, const float* __restrict__ g,
               const float* __restrict__ be, u16* __restrict__ out) {
  const int row = blockIdx.x;
  const int tid = threadIdx.x;
  const float4 v = ((const float4*)(x + (size_t)row * DM))[tid];
  float s  = v.x + v.y + v.z + v.w;
  float s2 = v.x * v.x + v.y * v.y + v.z * v.z + v.w * v.w;
  #pragma unroll
  for (int m = 1; m < 64; m <<= 1) {
    s  += __shfl_xor(s,  m, 64);
    s2 += __shfl_xor(s2, m, 64);
  }
  __shared__ float red[8];
  const int w = tid >> 6, lane = tid & 63;
  if (lane == 0) { red[w] = s; red[4 + w] = s2; }
  __syncthreads();
  s  = red[0] + red[1] + red[2] + red[3];
  s2 = red[4] + red[5] + red[6] + red[7];
  const float mu  = s * (1.0f / DM);
  const float var = s2 * (1.0f / DM) - mu * mu;
  const float rstd = rsqrtf(var + 1e-5f);
  const float4 gv = ((const float4*)g)[tid];
  const float4 bv = ((const float4*)be)[tid];
  u16x4 o;
  o[0] = f2b((v.x - mu) * rstd * gv.x + bv.x);
  o[1] = f2b((v.y - mu) * rstd * gv.y + bv.y);
  o[2] = f2b((v.z - mu) * rstd * gv.z + bv.z);
  o[3] = f2b((v.w - mu) * rstd * gv.w + bv.w);
  ((u16x4*)(out + (size_t)row * DM))[tid] = o;
}

// ---------------- combine (2-way): out = p0 + p1 + bias + resid (fp32) -----
__global__ __launch_bounds__(256)
void combine_kernel(const float4* __restrict__ p0, const float4* __restrict__ p1,
                    const float4* __restrict__ bias, const float4* __restrict__ resid,
                    float4* __restrict__ out, int total4, int colmask4) {
  for (int i = blockIdx.x * 256 + threadIdx.x; i < total4; i += gridDim.x * 256) {
    float4 a = p0[i], b = p1[i], bs = bias[i & colmask4], rr = resid[i];
    float4 o;
    o.x = a.x + b.x + bs.x + rr.x;
    o.y = a.y + b.y + bs.y + rr.y;
    o.z = a.z + b.z + bs.z + rr.z;
    o.w = a.w + b.w + bs.w + rr.w;
    out[i] = o;
  }
}

// ---------------- combine (4-way): out = Σp + bias + resid (fp32) ----------
__global__ __launch_bounds__(256)
void combine4_kernel(const float4* __restrict__ p0, const float4* __restrict__ p1,
                     const float4* __restrict__ p2, const float4* __restrict__ p3,
                     const float4* __restrict__ bias, const float4* __restrict__ resid,
                     float4* __restrict__ out, int total4, int colmask4) {
  for (int i = blockIdx.x * 256 + threadIdx.x; i < total4; i += gridDim.x * 256) {
    float4 a = p0[i], b = p1[i], c = p2[i], d = p3[i];
    float4 bs = bias[i & colmask4], rr = resid[i];
    float4 o;
    o.x = (a.x + b.x) + (c.x + d.x) + bs.x + rr.x;
    o.y = (a.y + b.y) + (c.y + d.y) + bs.y + rr.y;
    o.z = (a.z + b.z) + (c.z + d.z) + bs.z + rr.z;
    o.w = (a.w + b.w) + (c.w + d.w) + bs.w + rr.w;
    out[i] = o;
  }
}

// ------- fused 4-way combine + LayerNorm: x1 = Σp+bias+resid (fp32 out),
//         norm = LN(x1)*g+b (bf16 out, separate buffer) ---------------------
__global__ __launch_bounds__(256)
void combine4_ln_kernel(const float4* __restrict__ p0, const float4* __restrict__ p1,
                        const float4* __restrict__ p2, const float4* __restrict__ p3,
                        const float4* __restrict__ bias, const float4* __restrict__ resid,
                        float4* __restrict__ xout,
                        const float* __restrict__ g, const float* __restrict__ be,
                        u16* __restrict__ nout) {
  const int row = blockIdx.x;
  const int tid = threadIdx.x;
  const int i = row * (DM / 4) + tid;
  const float4 a = p0[i], b = p1[i], c = p2[i], d = p3[i];
  const float4 bs = bias[tid], rr = resid[i];
  float4 v;
  v.x = (a.x + b.x) + (c.x + d.x) + bs.x + rr.x;
  v.y = (a.y + b.y) + (c.y + d.y) + bs.y + rr.y;
  v.z = (a.z + b.z) + (c.z + d.z) + bs.z + rr.z;
  v.w = (a.w + b.w) + (c.w + d.w) + bs.w + rr.w;
  xout[i] = v;
  float s  = v.x + v.y + v.z + v.w;
  float s2 = v.x * v.x + v.y * v.y + v.z * v.z + v.w * v.w;
  #pragma unroll
  for (int m = 1; m < 64; m <<= 1) {
    s  += __shfl_xor(s,  m, 64);
    s2 += __shfl_xor(s2, m, 64);
  }
  __shared__ float red[8];
  const int w = tid >> 6, lane = tid & 63;
  if (lane == 0) { red[w] = s; red[4 + w] = s2; }
  __syncthreads();
  s  = red[0] + red[1] + red[2] + red[3];
  s2 = red[4] + red[5] + red[6] + red[7];
  const float mu  = s * (1.0f / DM);
  const float var = s2 * (1.0f / DM) - mu * mu;
  const float rstd = rsqrtf(var + 1e-5f);
  const float4 gv = ((const float4*)g)[tid];
  const float4 bv = ((const float4*)be)[tid];
  u16x4 o;
  o[0] = f2b((v.x - mu) * rstd * gv.x + bv.x);
  o[1] = f2b((v.y - mu) * rstd * gv.y + bv.y);
  o[2] = f2b((v.z - mu) * rstd * gv.z + bv.z);
  o[3] = f2b((v.w - mu) * rstd * gv.w + bv.w);
  ((u16x4*)(nout + (size_t)row * DM))[tid] = o;
}

// ---------------- GEMM: C[M,N] = A[M,K](bf16) * W[N,K](bf16)^T + bias ------
// 2-phase double-buffer at BK=32 (guide's verified minimum T3 recipe).
// __launch_bounds__(256,4): total VGPR+AGPR <= 128/wave (unified file).
// LDS swizzle chunk ^= (row>>1)&3 (2-way = free, m136), both-sides (rule #21).
// EPI 0 z==0 + vtrans: Q scaled by 0.125*log2(e) — head-dim scale AND the
// exp->exp2 domain change folded into the projection (cancels in softmax).
struct GemmPtrs { const u16* W[4]; const float* bias[4]; void* out[4];
                  const float* resid; int vtrans; };

template<int EPI>
__global__ __launch_bounds__(256, 4)
void gemm_bt(const u16* __restrict__ A, GemmPtrs p, int M, int N,
             int Kstride, int Kchunk) {
  __shared__ __align__(16) u16 As[2][128 * 32];
  __shared__ __align__(16) u16 Bs[2][128 * 32];
  const u16* __restrict__ Wm = p.W[blockIdx.z];
  const float* __restrict__ bias = p.bias[blockIdx.z];
  void* outv = p.out[blockIdx.z];
  const float* resid = p.resid;

  const int tid = threadIdx.x;
  const int lane = tid & 63;
  const int w = tid >> 6;
  const int brow = blockIdx.y * 128;
  const int bcol = blockIdx.x * 128;
  const int wr = (w >> 1) * 64, wc = (w & 1) * 64;
  const int koff = (EPI == 3) ? blockIdx.z * Kchunk : 0;

  f32x4 acc[4][4] = {};

  const int srow = tid >> 2;
  const int sc = ((tid & 3) ^ ((tid >> 3) & 3)) * 8;   // elements
  const int ldso = w * 512;                            // u16; +2048 for rows 64+

  const int nt = Kchunk >> 5;

  auto stage = [&](int t) {
    const int sl = t & 1;
    const int k0 = koff + t * 32;
    gl_lds16(&A [(size_t)(brow + srow) * Kstride + k0 + sc],      &As[sl][ldso]);
    gl_lds16(&A [(size_t)(brow + 64 + srow) * Kstride + k0 + sc], &As[sl][2048 + ldso]);
    gl_lds16(&Wm[(size_t)(bcol + srow) * Kstride + k0 + sc],      &Bs[sl][ldso]);
    gl_lds16(&Wm[(size_t)(bcol + 64 + srow) * Kstride + k0 + sc], &Bs[sl][2048 + ldso]);
  };

  stage(0);
  __syncthreads();

  for (int t = 0; t < nt; ++t) {
    if (t + 1 < nt) stage(t + 1);   // issue next-tile loads before compute
    const int sl = t & 1;
    bf16x8 a[4], b[4];
    #pragma unroll
    for (int f = 0; f < 4; ++f) {
      const int ra = wr + f * 16 + (lane & 15);
      a[f] = *(const bf16x8*)&As[sl][ra * 32 + ((lane >> 4) ^ ((ra >> 1) & 3)) * 8];
      const int rb = wc + f * 16 + (lane & 15);
      b[f] = *(const bf16x8*)&Bs[sl][rb * 32 + ((lane >> 4) ^ ((rb >> 1) & 3)) * 8];
    }
    #pragma unroll
    for (int fr = 0; fr < 4; ++fr)
      #pragma unroll
      for (int fc = 0; fc < 4; ++fc)
        acc[fr][fc] = __builtin_amdgcn_mfma_f32_16x16x32_bf16(a[fr], b[fc], acc[fr][fc], 0, 0, 0);
    __syncthreads();   // drains this iter's stage + all waves done with buf[sl]
  }

  const int orow0 = brow + wr + (lane >> 4) * 4;
  const int ocol0 = bcol + wc + (lane & 15);

  if (EPI == 0 && p.vtrans && blockIdx.z == 2) {
    // V projection written transposed: Vt[(b*DM + col)][s], s = row % SEQ
    #pragma unroll
    for (int fr = 0; fr < 4; ++fr) {
      const int row0 = orow0 + fr * 16;
      const int bq = row0 >> 11, s0 = row0 & (SEQ - 1);
      #pragma unroll
      for (int fc = 0; fc < 4; ++fc) {
        const int col = ocol0 + fc * 16;
        const float bvv = bias[col];
        u16x4 o;
        #pragma unroll
        for (int r = 0; r < 4; ++r) o[r] = f2b(acc[fr][fc][r] + bvv);
        *(u16x4*)((u16*)outv + (size_t)(bq * DM + col) * SEQ + s0) = o;
      }
    }
    return;
  }

  // 0.125 (1/sqrt(64)) * log2(e) — see attn (exp2-domain softmax)
  const float oscale = (EPI == 0 && p.vtrans && blockIdx.z == 0) ? 0.18033688011112042f : 1.0f;

  #pragma unroll
  for (int fr = 0; fr < 4; ++fr) {
    #pragma unroll
    for (int fc = 0; fc < 4; ++fc) {
      const int col = ocol0 + fc * 16;
      const float bvv = (EPI == 3) ? 0.0f : bias[col];
      #pragma unroll
      for (int r = 0; r < 4; ++r) {
        const int row = orow0 + fr * 16 + r;
        const size_t idx = (size_t)row * N + col;
        float v = acc[fr][fc][r] + bvv;
        if (EPI == 0) {
          ((u16*)outv)[idx] = f2b(v * oscale);
        } else if (EPI == 1) {
          float ge = 0.5f * v * (1.0f + erff(v * 0.70710678118654752f));
          ((u16*)outv)[idx] = f2b(ge);
        } else if (EPI == 2) {
          ((float*)outv)[idx] = v + resid[idx];
        } else {
          ((float*)outv)[idx] = v;   // partial, bias added in combine
        }
      }
    }
  }
}

// ---------------- flash attention, K-split x2 (flash-decoding) -------------
// R11 structure EXACTLY (serial max/sum chains — R13's tree+exp2f restructure
// regressed 70->84us) with ONE change: exp via __builtin_amdgcn_exp2f (bare
// v_exp_f32, scores pre-scaled into log2 domain) — removes the per-element
// v_mul of __expf without the OCML overhead plain exp2f added.
// THR 8 nats = 11.5 log2-units.
__global__ __launch_bounds__(128, 4)
void attn_kernel(const u16* __restrict__ Q, const u16* __restrict__ K,
                 const u16* __restrict__ Vt, float* __restrict__ Opart,
                 float2* __restrict__ ML, int ktps) {
  __shared__ __align__(16) u16 Ks[64 * 64];    // [k][d]
  __shared__ __align__(16) u16 Vts[64 * 64];   // [d][k]
  const int tid = threadIdx.x, lane = tid & 63, w = tid >> 6;
  const int bh = blockIdx.y, b = bh >> 4, h = bh & 15;
  const int kvh = blockIdx.z;
  const int q0 = blockIdx.x * 64 + w * 32;     // wave's q base
  const size_t base = (size_t)b * SEQ * DM + (size_t)h * DH;
  const size_t vbase = (size_t)(b * DM + h * DH) * SEQ;
  float* __restrict__ Op = Opart + (size_t)kvh * MROWS * DM;
  float2* __restrict__ mlp = ML + (size_t)kvh * 2 * NH * SEQ;

  const int l31 = lane & 31, hi = lane >> 5, l7 = l31 & 7;

  // Q fragments (B-operand): col=q=l31, k(d) = dt*16 + hi*8 + j
  bf16x8 qf[4];
  {
    const size_t qrow = base + (size_t)(q0 + l31) * DM;
    #pragma unroll
    for (int dt = 0; dt < 4; ++dt)
      qf[dt] = *(const bf16x8*)&Q[qrow + dt * 16 + hi * 8];
  }

  f32x16 oacc[2] = {};   // d-tiles 0-31, 32-63
  float mq = -1e30f, lq = 0.0f;   // for q = q0 + l31 (column layout)

  for (int kt = kvh * ktps; kt < (kvh + 1) * ktps; ++kt) {
    // stage K[64k][64d] and Vt[64d][64k], swizzled chunk = c ^ (row&7)
    #pragma unroll
    for (int i = 0; i < 4; ++i) {
      const int r0 = w * 32 + i * 8;            // wave-uniform LDS base row
      const int row = r0 + (lane >> 3);
      const int ch = ((lane & 7) ^ (row & 7)) * 8;
      gl_lds16(&K[base + (size_t)(kt * 64 + row) * DM + ch], &Ks[r0 * 64]);
      gl_lds16(&Vt[vbase + (size_t)row * SEQ + kt * 64 + ch], &Vts[r0 * 64]);
    }
    __syncthreads();

    #pragma unroll
    for (int sub = 0; sub < 2; ++sub) {         // 32-key sub-blocks
      // S^T (log2 domain) = sum_dt mfma32(Kfrag, Qfrag)
      f32x16 sacc = {};
      __builtin_amdgcn_s_setprio(1);
      #pragma unroll
      for (int dt = 0; dt < 4; ++dt) {
        bf16x8 kf = *(const bf16x8*)&Ks[(sub * 32 + l31) * 64 + (((dt << 1) | hi) ^ l7) * 8];
        sacc = __builtin_amdgcn_mfma_f32_32x32x16_bf16(kf, qf[dt], sacc, 0, 0, 0);
      }
      __builtin_amdgcn_s_setprio(0);

      // column max for q = l31 (serial chain + cross-half exchange, as R11)
      float tm = sacc[0];
      #pragma unroll
      for (int r = 1; r < 16; ++r) tm = fmaxf(tm, sacc[r]);
      tm = fmaxf(tm, __shfl_xor(tm, 32, 64));

      if (__any(tm > mq + 11.5f)) {
        const float mnew = fmaxf(mq, tm);
        const float fs = ex2(mq - mnew);
        mq = mnew;
        lq *= fs;
        #pragma unroll
        for (int r = 0; r < 16; ++r) {
          const float fsr = __shfl(fs, (r & 3) + 8 * (r >> 2) + 4 * hi, 64);
          oacc[0][r] *= fsr;
          oacc[1][r] *= fsr;
        }
      }

      // exp2 + pack into PV A-fragments (two k-slots of 16)
      uint32_t wd[2][4];
      float ps = 0.0f;
      #pragma unroll
      for (int half = 0; half < 2; ++half) {
        float p[8];
        #pragma unroll
        for (int j = 0; j < 8; ++j) {
          p[j] = ex2(sacc[half * 8 + j] - mq);
          ps += p[j];
        }
        const uint32_t a = pk2(p[0], p[1]), c = pk2(p[2], p[3]);
        const uint32_t bb = pk2(p[4], p[5]), d = pk2(p[6], p[7]);
        const uint32_t xa = (uint32_t)__shfl_xor((int)a, 32, 64);
        const uint32_t xb = (uint32_t)__shfl_xor((int)bb, 32, 64);
        const uint32_t xc = (uint32_t)__shfl_xor((int)c, 32, 64);
        const uint32_t xd = (uint32_t)__shfl_xor((int)d, 32, 64);
        wd[half][0] = hi ? xb : a;
        wd[half][1] = hi ? xd : c;
        wd[half][2] = hi ? bb : xa;
        wd[half][3] = hi ? d : xc;
      }
      lq += ps;
      bf16x8 pa0, pa1;
      #pragma unroll
      for (int j = 0; j < 4; ++j) {
        ((uint32_t*)&pa0)[j] = wd[0][j];
        ((uint32_t*)&pa1)[j] = wd[1][j];
      }

      // PV: oacc[dt] += pa[ks] * V[ks][dt]
      __builtin_amdgcn_s_setprio(1);
      #pragma unroll
      for (int dt = 0; dt < 2; ++dt) {
        #pragma unroll
        for (int ks = 0; ks < 2; ++ks) {
          bf16x8 vf = *(const bf16x8*)&Vts[(dt * 32 + l31) * 64 +
                                           (((sub << 2) | (ks << 1) | hi) ^ l7) * 8];
          oacc[dt] = __builtin_amdgcn_mfma_f32_32x32x16_bf16(ks ? pa1 : pa0, vf, oacc[dt], 0, 0, 0);
        }
      }
      __builtin_amdgcn_s_setprio(0);
    }
    __syncthreads();
  }

  // write unnormalized partials + (m, l) per q  (m in log2 domain)
  const float ltot = lq + __shfl_xor(lq, 32, 64);
  #pragma unroll
  for (int r = 0; r < 16; ++r) {
    const int crow = (r & 3) + 8 * (r >> 2) + 4 * hi;
    const size_t orow = base + (size_t)(q0 + crow) * DM;
    Op[orow + l31]      = oacc[0][r];
    Op[orow + 32 + l31] = oacc[1][r];
  }
  if (hi == 0) mlp[(size_t)bh * SEQ + q0 + l31] = make_float2(mq, ltot);
}

// ---------------- attn merge (2-way, log2-domain m) -------------------------
__global__ __launch_bounds__(256)
void attn_merge(const float4* __restrict__ Op0, const float4* __restrict__ Op1,
                const float2* __restrict__ ML, u16* __restrict__ ao) {
  const int row = blockIdx.x, tid = threadIdx.x;
  const int idx4 = row * (DM / 4) + tid;
  const int bh = ((row >> 11) << 4) | (tid >> 4);   // b*16 + h
  const int s = row & (SEQ - 1);
  const float2 a = ML[(size_t)bh * SEQ + s];
  const float2 c = ML[(size_t)(2 * NH) * SEQ + (size_t)bh * SEQ + s];
  const float m = fmaxf(a.x, c.x);
  const float f0 = ex2(a.x - m), f1 = ex2(c.x - m);
  const float inv = 1.0f / (a.y * f0 + c.y * f1);
  const float4 o0 = Op0[idx4], o1 = Op1[idx4];
  u16x4 o;
  o[0] = f2bn((o0.x * f0 + o1.x * f1) * inv);
  o[1] = f2bn((o0.y * f0 + o1.y * f1) * inv);
  o[2] = f2bn((o0.z * f0 + o1.z * f1) * inv);
  o[3] = f2bn((o0.w * f0 + o1.w * f1) * inv);
  ((u16x4*)ao)[idx4] = o;
}

// ---------------------------------------------------------------------------
extern "C" void kernel_launch(void* const* d_in, const int* in_sizes, int n_in,
                              void* d_out, int out_size, void* d_ws, size_t ws_size,
                              hipStream_t stream) {
  const float* x    = (const float*)d_in[0];
  const float* Wq   = (const float*)d_in[1];
  const float* bq   = (const float*)d_in[2];
  const float* Wk   = (const float*)d_in[3];
  const float* bk   = (const float*)d_in[4];
  const float* Wv   = (const float*)d_in[5];
  const float* bv   = (const float*)d_in[6];
  const float* Wo   = (const float*)d_in[7];
  const float* bo   = (const float*)d_in[8];
  const float* ln1g = (const float*)d_in[9];
  const float* ln1b = (const float*)d_in[10];
  const float* W1   = (const float*)d_in[11];
  const float* b1   = (const float*)d_in[12];
  const float* W2   = (const float*)d_in[13];
  const float* b2   = (const float*)d_in[14];
  const float* ln2g = (const float*)d_in[15];
  const float* ln2b = (const float*)d_in[16];
  float* out = (float*)d_out;

  char* wsb = (char*)d_ws;
  size_t off = 0;
  auto alloc = [&](size_t bytes) -> char* {
    char* pp = wsb + off;
    off += (bytes + 255) & ~(size_t)255;
    return pp;
  };
  u16* Wq_b = (u16*)alloc((size_t)DM * DM * 2);
  u16* Wk_b = (u16*)alloc((size_t)DM * DM * 2);
  u16* Wv_b = (u16*)alloc((size_t)DM * DM * 2);
  u16* Wo_b = (u16*)alloc((size_t)DM * DM * 2);
  u16* W1_b = (u16*)alloc((size_t)DFF * DM * 2);
  u16* W2_b = (u16*)alloc((size_t)DM * DFF * 2);
  u16* xn   = (u16*)alloc((size_t)MROWS * DM * 2);
  u16* qb   = (u16*)alloc((size_t)MROWS * DM * 2);
  u16* kb   = (u16*)alloc((size_t)MROWS * DM * 2);
  u16* vt   = (u16*)alloc((size_t)MROWS * DM * 2);  // transposed V
  u16* ao   = (u16*)alloc((size_t)MROWS * DM * 2);  // attn out, then LN2 out
  float2* ml = (float2*)alloc((size_t)2 * 2 * NH * SEQ * sizeof(float2));
  u16* h1   = (u16*)alloc((size_t)MROWS * DFF * 2); // FFN hidden; attn Op earlier
  float* pX = (float*)alloc((size_t)MROWS * DM * 4);
  float* pY = (float*)alloc((size_t)MROWS * DM * 4);
  const bool ws_x4 = (off <= ws_size);

  // fp32 partial buffers overlaid on dead regions:
  float* pA = (float*)xn;            // xn ∪ qb   (16 MB)
  float* pB = (float*)kb;            // kb ∪ vt   (16 MB)
  float* pC = (float*)h1;            // h1 lower  (16 MB) — dead during O-proj
  float* pD = (float*)((char*)h1 + (size_t)MROWS * DM * 4);  // h1 upper
  float* attnOp = (float*)h1;        // attention x2 partials (32 MB = h1)

  // 1. convert weights to bf16
  CvtArgs ca;
  ca.src[0] = Wq; ca.dst[0] = Wq_b; ca.n4[0] = DM * DM / 4;
  ca.src[1] = Wk; ca.dst[1] = Wk_b; ca.n4[1] = DM * DM / 4;
  ca.src[2] = Wv; ca.dst[2] = Wv_b; ca.n4[2] = DM * DM / 4;
  ca.src[3] = Wo; ca.dst[3] = Wo_b; ca.n4[3] = DM * DM / 4;
  ca.src[4] = W1; ca.dst[4] = W1_b; ca.n4[4] = DFF * DM / 4;
  ca.src[5] = W2; ca.dst[5] = W2_b; ca.n4[5] = DM * DFF / 4;
  cvt_kernel<<<2048, 256, 0, stream>>>(ca);

  // 2. LN1
  ln_kernel<<<MROWS, 256, 0, stream>>>(x, ln1g, ln1b, xn);

  // 3. QKV projections (z-fused; V transposed; Q pre-scaled 0.125*log2e)
  GemmPtrs pq = {};
  pq.W[0] = Wq_b; pq.W[1] = Wk_b; pq.W[2] = Wv_b;
  pq.bias[0] = bq; pq.bias[1] = bk; pq.bias[2] = bv;
  pq.out[0] = qb; pq.out[1] = kb; pq.out[2] = vt;
  pq.vtrans = 1;
  gemm_bt<0><<<dim3(DM / 128, MROWS / 128, 3), 256, 0, stream>>>(xn, pq, MROWS, DM, DM, DM);

  // 4. attention, K-split x2 -> fp32 partials + (m,l); merge -> ao (bf16)
  attn_kernel<<<dim3(SEQ / 64, 2 * NH, 2), 128, 0, stream>>>(qb, kb, vt, attnOp, ml,
                                                             SEQ / 64 / 2);
  attn_merge<<<MROWS, 256, 0, stream>>>((const float4*)attnOp,
                                        (const float4*)(attnOp + (size_t)MROWS * DM),
                                        (const float2*)ml, ao);

  // 5. output projection, K-split x4 -> partials; fused combine+bias+x+LN2
  GemmPtrs po = {};
  po.W[0] = po.W[1] = po.W[2] = po.W[3] = Wo_b;
  po.bias[0] = po.bias[1] = po.bias[2] = po.bias[3] = bo;
  po.out[0] = pA; po.out[1] = pB; po.out[2] = pC; po.out[3] = pD;
  gemm_bt<3><<<dim3(DM / 128, MROWS / 128, 4), 256, 0, stream>>>(ao, po, MROWS, DM, DM, DM / 4);
  combine4_ln_kernel<<<MROWS, 256, 0, stream>>>((const float4*)pA, (const float4*)pB,
                                                (const float4*)pC, (const float4*)pD,
                                                (const float4*)bo, (const float4*)x,
                                                (float4*)out, ln2g, ln2b, ao);

  // 6. FFN up + GELU (input: LN2 output in ao; h1 now free for FFN hidden)
  GemmPtrs p1 = {};
  p1.W[0] = W1_b; p1.bias[0] = b1; p1.out[0] = h1;
  gemm_bt<1><<<dim3(DFF / 128, MROWS / 128, 1), 256, 0, stream>>>(ao, p1, MROWS, DFF, DM, DM);

  // 7. FFN down, K-split (x4 if ws allows, else x2) -> partials -> combine
  if (ws_x4) {
    GemmPtrs p2 = {};
    p2.W[0] = p2.W[1] = p2.W[2] = p2.W[3] = W2_b;
    p2.bias[0] = p2.bias[1] = p2.bias[2] = p2.bias[3] = b2;
    p2.out[0] = pA; p2.out[1] = pB; p2.out[2] = pX; p2.out[3] = pY;
    gemm_bt<3><<<dim3(DM / 128, MROWS / 128, 4), 256, 0, stream>>>(h1, p2, MROWS, DM, DFF, DFF / 4);
    combine4_kernel<<<2048, 256, 0, stream>>>((const float4*)pA, (const float4*)pB,
                                              (const float4*)pX, (const float4*)pY,
                                              (const float4*)b2, (const float4*)out,
                                              (float4*)out, MROWS * DM / 4, DM / 4 - 1);
  } else {
    GemmPtrs p2 = {};
    p2.W[0] = p2.W[1] = W2_b;
    p2.bias[0] = p2.bias[1] = b2;
    p2.out[0] = pA; p2.out[1] = pB;
    gemm_bt<3><<<dim3(DM / 128, MROWS / 128, 2), 256, 0, stream>>>(h1, p2, MROWS, DM, DFF, DFF / 2);
    combine_kernel<<<2048, 256, 0, stream>>>((const float4*)pA, (const float4*)pB,
                                             (const float4*)b2, (const float4*)out,
                                             (float4*)out, MROWS * DM / 4, DM / 4 - 1);
  }
}

// Round 16
// 269.078 us; speedup vs baseline: 1.1171x; 1.0673x over previous
//
#include <hip/hip_runtime.h>
#include <hip/hip_bf16.h>
#include <stdint.h>

#define DM 1024
#define DFF 4096
#define NH 16
#define DH 64
#define SEQ 2048
#define MROWS 4096  // B*S

typedef unsigned short u16;
typedef __attribute__((ext_vector_type(8))) short bf16x8;
typedef __attribute__((ext_vector_type(4))) float f32x4;
typedef __attribute__((ext_vector_type(16))) float f32x16;
typedef __attribute__((ext_vector_type(4))) unsigned short u16x4;

__device__ __forceinline__ u16 f2b(float f) {
  union { float f; uint32_t u; } v; v.f = f;
  uint32_t r = v.u + 0x7FFFu + ((v.u >> 16) & 1u);
  return (u16)(r >> 16);
}

// native convert — clang emits v_cvt_pk_bf16_f32 for pairs (RNE)
__device__ __forceinline__ u16 f2bn(float f) {
  __hip_bfloat16 h = __float2bfloat16(f);
  return *reinterpret_cast<u16*>(&h);
}

__device__ __forceinline__ uint32_t pk2(float lo, float hi) {
  return (uint32_t)f2bn(lo) | ((uint32_t)f2bn(hi) << 16);
}

// bare v_exp_f32 (2^x) — no OCML wrapper (plain exp2f lowered to the precise
// OCML path and cost MORE VALU in R13; this is the R14-validated fast path)
__device__ __forceinline__ float ex2(float x) {
  return __builtin_amdgcn_exp2f(x);
}

__device__ __forceinline__ void gl_lds16(const void* g, void* l) {
  __builtin_amdgcn_global_load_lds(
      (const __attribute__((address_space(1))) uint32_t*)g,
      (__attribute__((address_space(3))) uint32_t*)l, 16, 0, 0);
}

// T1 bijective XCD swizzle (m204): nwg must be divisible by 8 (all ours are).
// XCD k (= bid%8 by HW round-robin) gets the contiguous original-id chunk
// [k*nwg/8, (k+1)*nwg/8) -> shared panels stay in one XCD's private L2.
__device__ __forceinline__ int xcd_orig(int bid, int nwg) {
  return (bid & 7) * (nwg >> 3) + (bid >> 3);
}

// ---------------- weight fp32 -> bf16 convert (all 6 weights, one kernel) --
struct CvtArgs { const float* src[6]; u16* dst[6]; int n4[6]; };

__global__ void cvt_kernel(CvtArgs a) {
  const int stride = gridDim.x * blockDim.x;
  const int t0 = blockIdx.x * blockDim.x + threadIdx.x;
  for (int i = 0; i < 6; ++i) {
    const float4* s = (const float4*)a.src[i];
    u16x4* d = (u16x4*)a.dst[i];
    const int n = a.n4[i];
    for (int idx = t0; idx < n; idx += stride) {
      float4 v = s[idx];
      u16x4 o;
      o[0] = f2b(v.x); o[1] = f2b(v.y); o[2] = f2b(v.z); o[3] = f2b(v.w);
      d[idx] = o;
    }
  }
}

// ---------------- fused LayerNorm: fp32 in -> bf16 out ---------------------
__global__ __launch_bounds__(256)
void ln_kernel(const float* __restrict__ x, const float* __restrict__ g,
               const float* __restrict__ be, u16* __restrict__ out) {
  const int row = blockIdx.x;
  const int tid = threadIdx.x;
  const float4 v = ((const float4*)(x + (size_t)row * DM))[tid];
  float s  = v.x + v.y + v.z + v.w;
  float s2 = v.x * v.x + v.y * v.y + v.z * v.z + v.w * v.w;
  #pragma unroll
  for (int m = 1; m < 64; m <<= 1) {
    s  += __shfl_xor(s,  m, 64);
    s2 += __shfl_xor(s2, m, 64);
  }
  __shared__ float red[8];
  const int w = tid >> 6, lane = tid & 63;
  if (lane == 0) { red[w] = s; red[4 + w] = s2; }
  __syncthreads();
  s  = red[0] + red[1] + red[2] + red[3];
  s2 = red[4] + red[5] + red[6] + red[7];
  const float mu  = s * (1.0f / DM);
  const float var = s2 * (1.0f / DM) - mu * mu;
  const float rstd = rsqrtf(var + 1e-5f);
  const float4 gv = ((const float4*)g)[tid];
  const float4 bv = ((const float4*)be)[tid];
  u16x4 o;
  o[0] = f2b((v.x - mu) * rstd * gv.x + bv.x);
  o[1] = f2b((v.y - mu) * rstd * gv.y + bv.y);
  o[2] = f2b((v.z - mu) * rstd * gv.z + bv.z);
  o[3] = f2b((v.w - mu) * rstd * gv.w + bv.w);
  ((u16x4*)(out + (size_t)row * DM))[tid] = o;
}

// ---------------- combine (2-way): out = p0 + p1 + bias + resid (fp32) -----
__global__ __launch_bounds__(256)
void combine_kernel(const float4* __restrict__ p0, const float4* __restrict__ p1,
                    const float4* __restrict__ bias, const float4* __restrict__ resid,
                    float4* __restrict__ out, int total4, int colmask4) {
  for (int i = blockIdx.x * 256 + threadIdx.x; i < total4; i += gridDim.x * 256) {
    float4 a = p0[i], b = p1[i], bs = bias[i & colmask4], rr = resid[i];
    float4 o;
    o.x = a.x + b.x + bs.x + rr.x;
    o.y = a.y + b.y + bs.y + rr.y;
    o.z = a.z + b.z + bs.z + rr.z;
    o.w = a.w + b.w + bs.w + rr.w;
    out[i] = o;
  }
}

// ---------------- combine (4-way): out = Σp + bias + resid (fp32) ----------
__global__ __launch_bounds__(256)
void combine4_kernel(const float4* __restrict__ p0, const float4* __restrict__ p1,
                     const float4* __restrict__ p2, const float4* __restrict__ p3,
                     const float4* __restrict__ bias, const float4* __restrict__ resid,
                     float4* __restrict__ out, int total4, int colmask4) {
  for (int i = blockIdx.x * 256 + threadIdx.x; i < total4; i += gridDim.x * 256) {
    float4 a = p0[i], b = p1[i], c = p2[i], d = p3[i];
    float4 bs = bias[i & colmask4], rr = resid[i];
    float4 o;
    o.x = (a.x + b.x) + (c.x + d.x) + bs.x + rr.x;
    o.y = (a.y + b.y) + (c.y + d.y) + bs.y + rr.y;
    o.z = (a.z + b.z) + (c.z + d.z) + bs.z + rr.z;
    o.w = (a.w + b.w) + (c.w + d.w) + bs.w + rr.w;
    out[i] = o;
  }
}

// ------- fused 4-way combine + LayerNorm: x1 = Σp+bias+resid (fp32 out),
//         norm = LN(x1)*g+b (bf16 out, separate buffer) ---------------------
__global__ __launch_bounds__(256)
void combine4_ln_kernel(const float4* __restrict__ p0, const float4* __restrict__ p1,
                        const float4* __restrict__ p2, const float4* __restrict__ p3,
                        const float4* __restrict__ bias, const float4* __restrict__ resid,
                        float4* __restrict__ xout,
                        const float* __restrict__ g, const float* __restrict__ be,
                        u16* __restrict__ nout) {
  const int row = blockIdx.x;
  const int tid = threadIdx.x;
  const int i = row * (DM / 4) + tid;
  const float4 a = p0[i], b = p1[i], c = p2[i], d = p3[i];
  const float4 bs = bias[tid], rr = resid[i];
  float4 v;
  v.x = (a.x + b.x) + (c.x + d.x) + bs.x + rr.x;
  v.y = (a.y + b.y) + (c.y + d.y) + bs.y + rr.y;
  v.z = (a.z + b.z) + (c.z + d.z) + bs.z + rr.z;
  v.w = (a.w + b.w) + (c.w + d.w) + bs.w + rr.w;
  xout[i] = v;
  float s  = v.x + v.y + v.z + v.w;
  float s2 = v.x * v.x + v.y * v.y + v.z * v.z + v.w * v.w;
  #pragma unroll
  for (int m = 1; m < 64; m <<= 1) {
    s  += __shfl_xor(s,  m, 64);
    s2 += __shfl_xor(s2, m, 64);
  }
  __shared__ float red[8];
  const int w = tid >> 6, lane = tid & 63;
  if (lane == 0) { red[w] = s; red[4 + w] = s2; }
  __syncthreads();
  s  = red[0] + red[1] + red[2] + red[3];
  s2 = red[4] + red[5] + red[6] + red[7];
  const float mu  = s * (1.0f / DM);
  const float var = s2 * (1.0f / DM) - mu * mu;
  const float rstd = rsqrtf(var + 1e-5f);
  const float4 gv = ((const float4*)g)[tid];
  const float4 bv = ((const float4*)be)[tid];
  u16x4 o;
  o[0] = f2b((v.x - mu) * rstd * gv.x + bv.x);
  o[1] = f2b((v.y - mu) * rstd * gv.y + bv.y);
  o[2] = f2b((v.z - mu) * rstd * gv.z + bv.z);
  o[3] = f2b((v.w - mu) * rstd * gv.w + bv.w);
  ((u16x4*)(nout + (size_t)row * DM))[tid] = o;
}

// ---------------- GEMM: C[M,N] = A[M,K](bf16) * W[N,K](bf16)^T + bias ------
// 2-phase double-buffer at BK=32; __launch_bounds__(256,4); 2-way-free LDS
// swizzle (all R11-verified). 1D grid + T1 XCD swizzle: XCD k owns a
// contiguous chunk of (z,y,x) tile space -> shared A/W panels stay in its L2.
struct GemmPtrs { const u16* W[4]; const float* bias[4]; void* out[4];
                  const float* resid; int vtrans; };

template<int EPI>
__global__ __launch_bounds__(256, 4)
void gemm_bt(const u16* __restrict__ A, GemmPtrs p, int M, int N,
             int Kstride, int Kchunk) {
  __shared__ __align__(16) u16 As[2][128 * 32];
  __shared__ __align__(16) u16 Bs[2][128 * 32];

  // decode T1-swizzled 1D block id -> (bx, by, bz); x fastest, z slowest
  const int nx = N >> 7, ny = M >> 7;
  const int orig = xcd_orig(blockIdx.x, gridDim.x);
  const int pp = nx * ny;
  const int bz = orig / pp;
  const int r2 = orig - bz * pp;
  const int by = r2 / nx;
  const int bx = r2 - by * nx;

  const u16* __restrict__ Wm = p.W[bz];
  const float* __restrict__ bias = p.bias[bz];
  void* outv = p.out[bz];
  const float* resid = p.resid;

  const int tid = threadIdx.x;
  const int lane = tid & 63;
  const int w = tid >> 6;
  const int brow = by * 128;
  const int bcol = bx * 128;
  const int wr = (w >> 1) * 64, wc = (w & 1) * 64;
  const int koff = (EPI == 3) ? bz * Kchunk : 0;

  f32x4 acc[4][4] = {};

  const int srow = tid >> 2;
  const int sc = ((tid & 3) ^ ((tid >> 3) & 3)) * 8;   // elements
  const int ldso = w * 512;                            // u16; +2048 for rows 64+

  const int nt = Kchunk >> 5;

  auto stage = [&](int t) {
    const int sl = t & 1;
    const int k0 = koff + t * 32;
    gl_lds16(&A [(size_t)(brow + srow) * Kstride + k0 + sc],      &As[sl][ldso]);
    gl_lds16(&A [(size_t)(brow + 64 + srow) * Kstride + k0 + sc], &As[sl][2048 + ldso]);
    gl_lds16(&Wm[(size_t)(bcol + srow) * Kstride + k0 + sc],      &Bs[sl][ldso]);
    gl_lds16(&Wm[(size_t)(bcol + 64 + srow) * Kstride + k0 + sc], &Bs[sl][2048 + ldso]);
  };

  stage(0);
  __syncthreads();

  for (int t = 0; t < nt; ++t) {
    if (t + 1 < nt) stage(t + 1);   // issue next-tile loads before compute
    const int sl = t & 1;
    bf16x8 a[4], b[4];
    #pragma unroll
    for (int f = 0; f < 4; ++f) {
      const int ra = wr + f * 16 + (lane & 15);
      a[f] = *(const bf16x8*)&As[sl][ra * 32 + ((lane >> 4) ^ ((ra >> 1) & 3)) * 8];
      const int rb = wc + f * 16 + (lane & 15);
      b[f] = *(const bf16x8*)&Bs[sl][rb * 32 + ((lane >> 4) ^ ((rb >> 1) & 3)) * 8];
    }
    #pragma unroll
    for (int fr = 0; fr < 4; ++fr)
      #pragma unroll
      for (int fc = 0; fc < 4; ++fc)
        acc[fr][fc] = __builtin_amdgcn_mfma_f32_16x16x32_bf16(a[fr], b[fc], acc[fr][fc], 0, 0, 0);
    __syncthreads();   // drains this iter's stage + all waves done with buf[sl]
  }

  const int orow0 = brow + wr + (lane >> 4) * 4;
  const int ocol0 = bcol + wc + (lane & 15);

  if (EPI == 0 && p.vtrans && bz == 2) {
    // V projection written transposed: Vt[(b*DM + col)][s], s = row % SEQ
    #pragma unroll
    for (int fr = 0; fr < 4; ++fr) {
      const int row0 = orow0 + fr * 16;
      const int bq = row0 >> 11, s0 = row0 & (SEQ - 1);
      #pragma unroll
      for (int fc = 0; fc < 4; ++fc) {
        const int col = ocol0 + fc * 16;
        const float bvv = bias[col];
        u16x4 o;
        #pragma unroll
        for (int r = 0; r < 4; ++r) o[r] = f2b(acc[fr][fc][r] + bvv);
        *(u16x4*)((u16*)outv + (size_t)(bq * DM + col) * SEQ + s0) = o;
      }
    }
    return;
  }

  // 0.125 (1/sqrt(64)) * log2(e) — see attn (exp2-domain softmax)
  const float oscale = (EPI == 0 && p.vtrans && bz == 0) ? 0.18033688011112042f : 1.0f;

  #pragma unroll
  for (int fr = 0; fr < 4; ++fr) {
    #pragma unroll
    for (int fc = 0; fc < 4; ++fc) {
      const int col = ocol0 + fc * 16;
      const float bvv = (EPI == 3) ? 0.0f : bias[col];
      #pragma unroll
      for (int r = 0; r < 4; ++r) {
        const int row = orow0 + fr * 16 + r;
        const size_t idx = (size_t)row * N + col;
        float v = acc[fr][fc][r] + bvv;
        if (EPI == 0) {
          ((u16*)outv)[idx] = f2b(v * oscale);
        } else if (EPI == 1) {
          float ge = 0.5f * v * (1.0f + erff(v * 0.70710678118654752f));
          ((u16*)outv)[idx] = f2b(ge);
        } else if (EPI == 2) {
          ((float*)outv)[idx] = v + resid[idx];
        } else {
          ((float*)outv)[idx] = v;   // partial, bias added in combine
        }
      }
    }
  }
}

// ---------------- flash attention, K-split x2 (flash-decoding) -------------
// R14 structure (exp2-domain softmax via bare v_exp_f32). 1D grid + T1 XCD
// swizzle: XCD k gets 256 contiguous original ids = 8 heads' q-blocks for
// one split -> that XCD's L2 holds just those heads' K/V halves (8*256KB =
// 2MB <= 4MB), ending the 8-way cross-XCD K/V replication (R14 FETCH was
// 72.9MB vs ~24MB unique). Original id layout: x(32) | bh(32) | z(2).
__global__ __launch_bounds__(128, 4)
void attn_kernel(const u16* __restrict__ Q, const u16* __restrict__ K,
                 const u16* __restrict__ Vt, float* __restrict__ Opart,
                 float2* __restrict__ ML, int ktps) {
  __shared__ __align__(16) u16 Ks[64 * 64];    // [k][d]
  __shared__ __align__(16) u16 Vts[64 * 64];   // [d][k]
  const int tid = threadIdx.x, lane = tid & 63, w = tid >> 6;

  const int orig = xcd_orig(blockIdx.x, gridDim.x);
  const int bxq = orig & 31;            // q-block (SEQ/64 = 32)
  const int bh = (orig >> 5) & 31;      // b*16 + h
  const int kvh = orig >> 10;           // key split

  const int b = bh >> 4, h = bh & 15;
  const int q0 = bxq * 64 + w * 32;     // wave's q base
  const size_t base = (size_t)b * SEQ * DM + (size_t)h * DH;
  const size_t vbase = (size_t)(b * DM + h * DH) * SEQ;
  float* __restrict__ Op = Opart + (size_t)kvh * MROWS * DM;
  float2* __restrict__ mlp = ML + (size_t)kvh * 2 * NH * SEQ;

  const int l31 = lane & 31, hi = lane >> 5, l7 = l31 & 7;

  // Q fragments (B-operand): col=q=l31, k(d) = dt*16 + hi*8 + j
  bf16x8 qf[4];
  {
    const size_t qrow = base + (size_t)(q0 + l31) * DM;
    #pragma unroll
    for (int dt = 0; dt < 4; ++dt)
      qf[dt] = *(const bf16x8*)&Q[qrow + dt * 16 + hi * 8];
  }

  f32x16 oacc[2] = {};   // d-tiles 0-31, 32-63
  float mq = -1e30f, lq = 0.0f;   // for q = q0 + l31 (column layout)

  for (int kt = kvh * ktps; kt < (kvh + 1) * ktps; ++kt) {
    // stage K[64k][64d] and Vt[64d][64k], swizzled chunk = c ^ (row&7)
    #pragma unroll
    for (int i = 0; i < 4; ++i) {
      const int r0 = w * 32 + i * 8;            // wave-uniform LDS base row
      const int row = r0 + (lane >> 3);
      const int ch = ((lane & 7) ^ (row & 7)) * 8;
      gl_lds16(&K[base + (size_t)(kt * 64 + row) * DM + ch], &Ks[r0 * 64]);
      gl_lds16(&Vt[vbase + (size_t)row * SEQ + kt * 64 + ch], &Vts[r0 * 64]);
    }
    __syncthreads();

    #pragma unroll
    for (int sub = 0; sub < 2; ++sub) {         // 32-key sub-blocks
      // S^T (log2 domain) = sum_dt mfma32(Kfrag, Qfrag)
      f32x16 sacc = {};
      __builtin_amdgcn_s_setprio(1);
      #pragma unroll
      for (int dt = 0; dt < 4; ++dt) {
        bf16x8 kf = *(const bf16x8*)&Ks[(sub * 32 + l31) * 64 + (((dt << 1) | hi) ^ l7) * 8];
        sacc = __builtin_amdgcn_mfma_f32_32x32x16_bf16(kf, qf[dt], sacc, 0, 0, 0);
      }
      __builtin_amdgcn_s_setprio(0);

      // column max for q = l31 (serial chain + cross-half exchange)
      float tm = sacc[0];
      #pragma unroll
      for (int r = 1; r < 16; ++r) tm = fmaxf(tm, sacc[r]);
      tm = fmaxf(tm, __shfl_xor(tm, 32, 64));

      if (__any(tm > mq + 11.5f)) {
        const float mnew = fmaxf(mq, tm);
        const float fs = ex2(mq - mnew);
        mq = mnew;
        lq *= fs;
        #pragma unroll
        for (int r = 0; r < 16; ++r) {
          const float fsr = __shfl(fs, (r & 3) + 8 * (r >> 2) + 4 * hi, 64);
          oacc[0][r] *= fsr;
          oacc[1][r] *= fsr;
        }
      }

      // exp2 + pack into PV A-fragments (two k-slots of 16)
      uint32_t wd[2][4];
      float ps = 0.0f;
      #pragma unroll
      for (int half = 0; half < 2; ++half) {
        float p[8];
        #pragma unroll
        for (int j = 0; j < 8; ++j) {
          p[j] = ex2(sacc[half * 8 + j] - mq);
          ps += p[j];
        }
        const uint32_t a = pk2(p[0], p[1]), c = pk2(p[2], p[3]);
        const uint32_t bb = pk2(p[4], p[5]), d = pk2(p[6], p[7]);
        const uint32_t xa = (uint32_t)__shfl_xor((int)a, 32, 64);
        const uint32_t xb = (uint32_t)__shfl_xor((int)bb, 32, 64);
        const uint32_t xc = (uint32_t)__shfl_xor((int)c, 32, 64);
        const uint32_t xd = (uint32_t)__shfl_xor((int)d, 32, 64);
        wd[half][0] = hi ? xb : a;
        wd[half][1] = hi ? xd : c;
        wd[half][2] = hi ? bb : xa;
        wd[half][3] = hi ? d : xc;
      }
      lq += ps;
      bf16x8 pa0, pa1;
      #pragma unroll
      for (int j = 0; j < 4; ++j) {
        ((uint32_t*)&pa0)[j] = wd[0][j];
        ((uint32_t*)&pa1)[j] = wd[1][j];
      }

      // PV: oacc[dt] += pa[ks] * V[ks][dt]
      __builtin_amdgcn_s_setprio(1);
      #pragma unroll
      for (int dt = 0; dt < 2; ++dt) {
        #pragma unroll
        for (int ks = 0; ks < 2; ++ks) {
          bf16x8 vf = *(const bf16x8*)&Vts[(dt * 32 + l31) * 64 +
                                           (((sub << 2) | (ks << 1) | hi) ^ l7) * 8];
          oacc[dt] = __builtin_amdgcn_mfma_f32_32x32x16_bf16(ks ? pa1 : pa0, vf, oacc[dt], 0, 0, 0);
        }
      }
      __builtin_amdgcn_s_setprio(0);
    }
    __syncthreads();
  }

  // write unnormalized partials + (m, l) per q  (m in log2 domain)
  const float ltot = lq + __shfl_xor(lq, 32, 64);
  #pragma unroll
  for (int r = 0; r < 16; ++r) {
    const int crow = (r & 3) + 8 * (r >> 2) + 4 * hi;
    const size_t orow = base + (size_t)(q0 + crow) * DM;
    Op[orow + l31]      = oacc[0][r];
    Op[orow + 32 + l31] = oacc[1][r];
  }
  if (hi == 0) mlp[(size_t)bh * SEQ + q0 + l31] = make_float2(mq, ltot);
}

// ---------------- attn merge (2-way, log2-domain m) -------------------------
__global__ __launch_bounds__(256)
void attn_merge(const float4* __restrict__ Op0, const float4* __restrict__ Op1,
                const float2* __restrict__ ML, u16* __restrict__ ao) {
  const int row = blockIdx.x, tid = threadIdx.x;
  const int idx4 = row * (DM / 4) + tid;
  const int bh = ((row >> 11) << 4) | (tid >> 4);   // b*16 + h
  const int s = row & (SEQ - 1);
  const float2 a = ML[(size_t)bh * SEQ + s];
  const float2 c = ML[(size_t)(2 * NH) * SEQ + (size_t)bh * SEQ + s];
  const float m = fmaxf(a.x, c.x);
  const float f0 = ex2(a.x - m), f1 = ex2(c.x - m);
  const float inv = 1.0f / (a.y * f0 + c.y * f1);
  const float4 o0 = Op0[idx4], o1 = Op1[idx4];
  u16x4 o;
  o[0] = f2bn((o0.x * f0 + o1.x * f1) * inv);
  o[1] = f2bn((o0.y * f0 + o1.y * f1) * inv);
  o[2] = f2bn((o0.z * f0 + o1.z * f1) * inv);
  o[3] = f2bn((o0.w * f0 + o1.w * f1) * inv);
  ((u16x4*)ao)[idx4] = o;
}

// ---------------------------------------------------------------------------
extern "C" void kernel_launch(void* const* d_in, const int* in_sizes, int n_in,
                              void* d_out, int out_size, void* d_ws, size_t ws_size,
                              hipStream_t stream) {
  const float* x    = (const float*)d_in[0];
  const float* Wq   = (const float*)d_in[1];
  const float* bq   = (const float*)d_in[2];
  const float* Wk   = (const float*)d_in[3];
  const float* bk   = (const float*)d_in[4];
  const float* Wv   = (const float*)d_in[5];
  const float* bv   = (const float*)d_in[6];
  const float* Wo   = (const float*)d_in[7];
  const float* bo   = (const float*)d_in[8];
  const float* ln1g = (const float*)d_in[9];
  const float* ln1b = (const float*)d_in[10];
  const float* W1   = (const float*)d_in[11];
  const float* b1   = (const float*)d_in[12];
  const float* W2   = (const float*)d_in[13];
  const float* b2   = (const float*)d_in[14];
  const float* ln2g = (const float*)d_in[15];
  const float* ln2b = (const float*)d_in[16];
  float* out = (float*)d_out;

  char* wsb = (char*)d_ws;
  size_t off = 0;
  auto alloc = [&](size_t bytes) -> char* {
    char* pp = wsb + off;
    off += (bytes + 255) & ~(size_t)255;
    return pp;
  };
  u16* Wq_b = (u16*)alloc((size_t)DM * DM * 2);
  u16* Wk_b = (u16*)alloc((size_t)DM * DM * 2);
  u16* Wv_b = (u16*)alloc((size_t)DM * DM * 2);
  u16* Wo_b = (u16*)alloc((size_t)DM * DM * 2);
  u16* W1_b = (u16*)alloc((size_t)DFF * DM * 2);
  u16* W2_b = (u16*)alloc((size_t)DM * DFF * 2);
  u16* xn   = (u16*)alloc((size_t)MROWS * DM * 2);
  u16* qb   = (u16*)alloc((size_t)MROWS * DM * 2);
  u16* kb   = (u16*)alloc((size_t)MROWS * DM * 2);
  u16* vt   = (u16*)alloc((size_t)MROWS * DM * 2);  // transposed V
  u16* ao   = (u16*)alloc((size_t)MROWS * DM * 2);  // attn out, then LN2 out
  float2* ml = (float2*)alloc((size_t)2 * 2 * NH * SEQ * sizeof(float2));
  u16* h1   = (u16*)alloc((size_t)MROWS * DFF * 2); // FFN hidden; attn Op earlier
  float* pX = (float*)alloc((size_t)MROWS * DM * 4);
  float* pY = (float*)alloc((size_t)MROWS * DM * 4);
  const bool ws_x4 = (off <= ws_size);

  // fp32 partial buffers overlaid on dead regions:
  float* pA = (float*)xn;            // xn ∪ qb   (16 MB)
  float* pB = (float*)kb;            // kb ∪ vt   (16 MB)
  float* pC = (float*)h1;            // h1 lower  (16 MB) — dead during O-proj
  float* pD = (float*)((char*)h1 + (size_t)MROWS * DM * 4);  // h1 upper
  float* attnOp = (float*)h1;        // attention x2 partials (32 MB = h1)

  // 1. convert weights to bf16
  CvtArgs ca;
  ca.src[0] = Wq; ca.dst[0] = Wq_b; ca.n4[0] = DM * DM / 4;
  ca.src[1] = Wk; ca.dst[1] = Wk_b; ca.n4[1] = DM * DM / 4;
  ca.src[2] = Wv; ca.dst[2] = Wv_b; ca.n4[2] = DM * DM / 4;
  ca.src[3] = Wo; ca.dst[3] = Wo_b; ca.n4[3] = DM * DM / 4;
  ca.src[4] = W1; ca.dst[4] = W1_b; ca.n4[4] = DFF * DM / 4;
  ca.src[5] = W2; ca.dst[5] = W2_b; ca.n4[5] = DM * DFF / 4;
  cvt_kernel<<<2048, 256, 0, stream>>>(ca);

  // 2. LN1
  ln_kernel<<<MROWS, 256, 0, stream>>>(x, ln1g, ln1b, xn);

  // 3. QKV projections (z-fused; V transposed; Q pre-scaled 0.125*log2e)
  GemmPtrs pq = {};
  pq.W[0] = Wq_b; pq.W[1] = Wk_b; pq.W[2] = Wv_b;
  pq.bias[0] = bq; pq.bias[1] = bk; pq.bias[2] = bv;
  pq.out[0] = qb; pq.out[1] = kb; pq.out[2] = vt;
  pq.vtrans = 1;
  gemm_bt<0><<<(DM / 128) * (MROWS / 128) * 3, 256, 0, stream>>>(xn, pq, MROWS, DM, DM, DM);

  // 4. attention, K-split x2 -> fp32 partials + (m,l); merge -> ao (bf16)
  attn_kernel<<<(SEQ / 64) * 2 * NH * 2, 128, 0, stream>>>(qb, kb, vt, attnOp, ml,
                                                           SEQ / 64 / 2);
  attn_merge<<<MROWS, 256, 0, stream>>>((const float4*)attnOp,
                                        (const float4*)(attnOp + (size_t)MROWS * DM),
                                        (const float2*)ml, ao);

  // 5. output projection, K-split x4 -> partials; fused combine+bias+x+LN2
  GemmPtrs po = {};
  po.W[0] = po.W[1] = po.W[2] = po.W[3] = Wo_b;
  po.bias[0] = po.bias[1] = po.bias[2] = po.bias[3] = bo;
  po.out[0] = pA; po.out[1] = pB; po.out[2] = pC; po.out[3] = pD;
  gemm_bt<3><<<(DM / 128) * (MROWS / 128) * 4, 256, 0, stream>>>(ao, po, MROWS, DM, DM, DM / 4);
  combine4_ln_kernel<<<MROWS, 256, 0, stream>>>((const float4*)pA, (const float4*)pB,
                                                (const float4*)pC, (const float4*)pD,
                                                (const float4*)bo, (const float4*)x,
                                                (float4*)out, ln2g, ln2b, ao);

  // 6. FFN up + GELU (input: LN2 output in ao; h1 now free for FFN hidden)
  GemmPtrs p1 = {};
  p1.W[0] = W1_b; p1.bias[0] = b1; p1.out[0] = h1;
  gemm_bt<1><<<(DFF / 128) * (MROWS / 128), 256, 0, stream>>>(ao, p1, MROWS, DFF, DM, DM);

  // 7. FFN down, K-split (x4 if ws allows, else x2) -> partials -> combine
  if (ws_x4) {
    GemmPtrs p2 = {};
    p2.W[0] = p2.W[1] = p2.W[2] = p2.W[3] = W2_b;
    p2.bias[0] = p2.bias[1] = p2.bias[2] = p2.bias[3] = b2;
    p2.out[0] = pA; p2.out[1] = pB; p2.out[2] = pX; p2.out[3] = pY;
    gemm_bt<3><<<(DM / 128) * (MROWS / 128) * 4, 256, 0, stream>>>(h1, p2, MROWS, DM, DFF, DFF / 4);
    combine4_kernel<<<2048, 256, 0, stream>>>((const float4*)pA, (const float4*)pB,
                                              (const float4*)pX, (const float4*)pY,
                                              (const float4*)b2, (const float4*)out,
                                              (float4*)out, MROWS * DM / 4, DM / 4 - 1);
  } else {
    GemmPtrs p2 = {};
    p2.W[0] = p2.W[1] = W2_b;
    p2.bias[0] = p2.bias[1] = b2;
    p2.out[0] = pA; p2.out[1] = pB;
    gemm_bt<3><<<(DM / 128) * (MROWS / 128) * 2, 256, 0, stream>>>(h1, p2, MROWS, DM, DFF, DFF / 2);
    combine_kernel<<<2048, 256, 0, stream>>>((const float4*)pA, (const float4*)pB,
                                             (const float4*)b2, (const float4*)out,
                                             (float4*)out, MROWS * DM / 4, DM / 4 - 1);
  }
}

// Round 17
// 255.775 us; speedup vs baseline: 1.1752x; 1.0520x over previous
//
#include <hip/hip_runtime.h>
#include <hip/hip_bf16.h>
#include <stdint.h>

#define DM 1024
#define DFF 4096
#define NH 16
#define DH 64
#define SEQ 2048
#define MROWS 4096  // B*S

typedef unsigned short u16;
typedef __attribute__((ext_vector_type(8))) short bf16x8;
typedef __attribute__((ext_vector_type(4))) float f32x4;
typedef __attribute__((ext_vector_type(16))) float f32x16;
typedef __attribute__((ext_vector_type(4))) unsigned short u16x4;

__device__ __forceinline__ u16 f2b(float f) {
  union { float f; uint32_t u; } v; v.f = f;
  uint32_t r = v.u + 0x7FFFu + ((v.u >> 16) & 1u);
  return (u16)(r >> 16);
}

// native convert — clang emits v_cvt_pk_bf16_f32 for pairs (RNE)
__device__ __forceinline__ u16 f2bn(float f) {
  __hip_bfloat16 h = __float2bfloat16(f);
  return *reinterpret_cast<u16*>(&h);
}

__device__ __forceinline__ float b2f(u16 v) {
  union { uint32_t u; float f; } t; t.u = (uint32_t)v << 16; return t.f;
}

__device__ __forceinline__ uint32_t pk2(float lo, float hi) {
  return (uint32_t)f2bn(lo) | ((uint32_t)f2bn(hi) << 16);
}

// bare v_exp_f32 (2^x) — R14-validated fast path (plain exp2f lowers to OCML)
__device__ __forceinline__ float ex2(float x) {
  return __builtin_amdgcn_exp2f(x);
}

__device__ __forceinline__ void gl_lds16(const void* g, void* l) {
  __builtin_amdgcn_global_load_lds(
      (const __attribute__((address_space(1))) uint32_t*)g,
      (__attribute__((address_space(3))) uint32_t*)l, 16, 0, 0);
}

// T1 bijective XCD swizzle (m204): XCD k (= bid%8) gets contiguous orig-id
// chunk [k*nwg/8,(k+1)*nwg/8) -> shared panels stay in one XCD's L2.
// R15: attn FETCH 72.9->19.0 MB, total -18us.
__device__ __forceinline__ int xcd_orig(int bid, int nwg) {
  return (bid & 7) * (nwg >> 3) + (bid >> 3);
}

// ---------------- weight fp32 -> bf16 convert (all 6 weights, one kernel) --
struct CvtArgs { const float* src[6]; u16* dst[6]; int n4[6]; };

__global__ void cvt_kernel(CvtArgs a) {
  const int stride = gridDim.x * blockDim.x;
  const int t0 = blockIdx.x * blockDim.x + threadIdx.x;
  for (int i = 0; i < 6; ++i) {
    const float4* s = (const float4*)a.src[i];
    u16x4* d = (u16x4*)a.dst[i];
    const int n = a.n4[i];
    for (int idx = t0; idx < n; idx += stride) {
      float4 v = s[idx];
      u16x4 o;
      o[0] = f2b(v.x); o[1] = f2b(v.y); o[2] = f2b(v.z); o[3] = f2b(v.w);
      d[idx] = o;
    }
  }
}

// ---------------- fused LayerNorm: fp32 in -> bf16 out ---------------------
__global__ __launch_bounds__(256)
void ln_kernel(const float* __restrict__ x, const float* __restrict__ g,
               const float* __restrict__ be, u16* __restrict__ out) {
  const int row = blockIdx.x;
  const int tid = threadIdx.x;
  const float4 v = ((const float4*)(x + (size_t)row * DM))[tid];
  float s  = v.x + v.y + v.z + v.w;
  float s2 = v.x * v.x + v.y * v.y + v.z * v.z + v.w * v.w;
  #pragma unroll
  for (int m = 1; m < 64; m <<= 1) {
    s  += __shfl_xor(s,  m, 64);
    s2 += __shfl_xor(s2, m, 64);
  }
  __shared__ float red[8];
  const int w = tid >> 6, lane = tid & 63;
  if (lane == 0) { red[w] = s; red[4 + w] = s2; }
  __syncthreads();
  s  = red[0] + red[1] + red[2] + red[3];
  s2 = red[4] + red[5] + red[6] + red[7];
  const float mu  = s * (1.0f / DM);
  const float var = s2 * (1.0f / DM) - mu * mu;
  const float rstd = rsqrtf(var + 1e-5f);
  const float4 gv = ((const float4*)g)[tid];
  const float4 bv = ((const float4*)be)[tid];
  u16x4 o;
  o[0] = f2b((v.x - mu) * rstd * gv.x + bv.x);
  o[1] = f2b((v.y - mu) * rstd * gv.y + bv.y);
  o[2] = f2b((v.z - mu) * rstd * gv.z + bv.z);
  o[3] = f2b((v.w - mu) * rstd * gv.w + bv.w);
  ((u16x4*)(out + (size_t)row * DM))[tid] = o;
}

// ---------------- combine (2-way, bf16 partials) ---------------------------
__global__ __launch_bounds__(256)
void combine_kernel(const u16x4* __restrict__ p0, const u16x4* __restrict__ p1,
                    const float4* __restrict__ bias, const float4* __restrict__ resid,
                    float4* __restrict__ out, int total4, int colmask4) {
  for (int i = blockIdx.x * 256 + threadIdx.x; i < total4; i += gridDim.x * 256) {
    u16x4 a = p0[i], b = p1[i];
    float4 bs = bias[i & colmask4], rr = resid[i];
    float4 o;
    o.x = b2f(a[0]) + b2f(b[0]) + bs.x + rr.x;
    o.y = b2f(a[1]) + b2f(b[1]) + bs.y + rr.y;
    o.z = b2f(a[2]) + b2f(b[2]) + bs.z + rr.z;
    o.w = b2f(a[3]) + b2f(b[3]) + bs.w + rr.w;
    out[i] = o;
  }
}

// ---------------- combine (4-way, bf16 partials) ---------------------------
__global__ __launch_bounds__(256)
void combine4_kernel(const u16x4* __restrict__ p0, const u16x4* __restrict__ p1,
                     const u16x4* __restrict__ p2, const u16x4* __restrict__ p3,
                     const float4* __restrict__ bias, const float4* __restrict__ resid,
                     float4* __restrict__ out, int total4, int colmask4) {
  for (int i = blockIdx.x * 256 + threadIdx.x; i < total4; i += gridDim.x * 256) {
    u16x4 a = p0[i], b = p1[i], c = p2[i], d = p3[i];
    float4 bs = bias[i & colmask4], rr = resid[i];
    float4 o;
    o.x = (b2f(a[0]) + b2f(b[0])) + (b2f(c[0]) + b2f(d[0])) + bs.x + rr.x;
    o.y = (b2f(a[1]) + b2f(b[1])) + (b2f(c[1]) + b2f(d[1])) + bs.y + rr.y;
    o.z = (b2f(a[2]) + b2f(b[2])) + (b2f(c[2]) + b2f(d[2])) + bs.z + rr.z;
    o.w = (b2f(a[3]) + b2f(b[3])) + (b2f(c[3]) + b2f(d[3])) + bs.w + rr.w;
    out[i] = o;
  }
}

// ------- fused 4-way combine (bf16 partials) + LayerNorm -------------------
__global__ __launch_bounds__(256)
void combine4_ln_kernel(const u16x4* __restrict__ p0, const u16x4* __restrict__ p1,
                        const u16x4* __restrict__ p2, const u16x4* __restrict__ p3,
                        const float4* __restrict__ bias, const float4* __restrict__ resid,
                        float4* __restrict__ xout,
                        const float* __restrict__ g, const float* __restrict__ be,
                        u16* __restrict__ nout) {
  const int row = blockIdx.x;
  const int tid = threadIdx.x;
  const int i = row * (DM / 4) + tid;
  const u16x4 a = p0[i], b = p1[i], c = p2[i], d = p3[i];
  const float4 bs = bias[tid], rr = resid[i];
  float4 v;
  v.x = (b2f(a[0]) + b2f(b[0])) + (b2f(c[0]) + b2f(d[0])) + bs.x + rr.x;
  v.y = (b2f(a[1]) + b2f(b[1])) + (b2f(c[1]) + b2f(d[1])) + bs.y + rr.y;
  v.z = (b2f(a[2]) + b2f(b[2])) + (b2f(c[2]) + b2f(d[2])) + bs.z + rr.z;
  v.w = (b2f(a[3]) + b2f(b[3])) + (b2f(c[3]) + b2f(d[3])) + bs.w + rr.w;
  xout[i] = v;
  float s  = v.x + v.y + v.z + v.w;
  float s2 = v.x * v.x + v.y * v.y + v.z * v.z + v.w * v.w;
  #pragma unroll
  for (int m = 1; m < 64; m <<= 1) {
    s  += __shfl_xor(s,  m, 64);
    s2 += __shfl_xor(s2, m, 64);
  }
  __shared__ float red[8];
  const int w = tid >> 6, lane = tid & 63;
  if (lane == 0) { red[w] = s; red[4 + w] = s2; }
  __syncthreads();
  s  = red[0] + red[1] + red[2] + red[3];
  s2 = red[4] + red[5] + red[6] + red[7];
  const float mu  = s * (1.0f / DM);
  const float var = s2 * (1.0f / DM) - mu * mu;
  const float rstd = rsqrtf(var + 1e-5f);
  const float4 gv = ((const float4*)g)[tid];
  const float4 bv = ((const float4*)be)[tid];
  u16x4 o;
  o[0] = f2b((v.x - mu) * rstd * gv.x + bv.x);
  o[1] = f2b((v.y - mu) * rstd * gv.y + bv.y);
  o[2] = f2b((v.z - mu) * rstd * gv.z + bv.z);
  o[3] = f2b((v.w - mu) * rstd * gv.w + bv.w);
  ((u16x4*)(nout + (size_t)row * DM))[tid] = o;
}

// ---------------- GEMM: C[M,N] = A[M,K](bf16) * W[N,K](bf16)^T + bias ------
// 2-phase double-buffer at BK=32; __launch_bounds__(256,4); 2-way-free LDS
// swizzle; 1D grid + T1 XCD swizzle (all verified R11/R15).
// EPI 3 now writes bf16 partials (0.2% relative — cancels/negligible after
// combine; halves partial write+read traffic, the dominant elementwise cost).
struct GemmPtrs { const u16* W[4]; const float* bias[4]; void* out[4];
                  const float* resid; int vtrans; };

template<int EPI>
__global__ __launch_bounds__(256, 4)
void gemm_bt(const u16* __restrict__ A, GemmPtrs p, int M, int N,
             int Kstride, int Kchunk) {
  __shared__ __align__(16) u16 As[2][128 * 32];
  __shared__ __align__(16) u16 Bs[2][128 * 32];

  // decode T1-swizzled 1D block id -> (bx, by, bz); x fastest, z slowest
  const int nx = N >> 7, ny = M >> 7;
  const int orig = xcd_orig(blockIdx.x, gridDim.x);
  const int pp = nx * ny;
  const int bz = orig / pp;
  const int r2 = orig - bz * pp;
  const int by = r2 / nx;
  const int bx = r2 - by * nx;

  const u16* __restrict__ Wm = p.W[bz];
  const float* __restrict__ bias = p.bias[bz];
  void* outv = p.out[bz];
  const float* resid = p.resid;

  const int tid = threadIdx.x;
  const int lane = tid & 63;
  const int w = tid >> 6;
  const int brow = by * 128;
  const int bcol = bx * 128;
  const int wr = (w >> 1) * 64, wc = (w & 1) * 64;
  const int koff = (EPI == 3) ? bz * Kchunk : 0;

  f32x4 acc[4][4] = {};

  const int srow = tid >> 2;
  const int sc = ((tid & 3) ^ ((tid >> 3) & 3)) * 8;   // elements
  const int ldso = w * 512;                            // u16; +2048 for rows 64+

  const int nt = Kchunk >> 5;

  auto stage = [&](int t) {
    const int sl = t & 1;
    const int k0 = koff + t * 32;
    gl_lds16(&A [(size_t)(brow + srow) * Kstride + k0 + sc],      &As[sl][ldso]);
    gl_lds16(&A [(size_t)(brow + 64 + srow) * Kstride + k0 + sc], &As[sl][2048 + ldso]);
    gl_lds16(&Wm[(size_t)(bcol + srow) * Kstride + k0 + sc],      &Bs[sl][ldso]);
    gl_lds16(&Wm[(size_t)(bcol + 64 + srow) * Kstride + k0 + sc], &Bs[sl][2048 + ldso]);
  };

  stage(0);
  __syncthreads();

  for (int t = 0; t < nt; ++t) {
    if (t + 1 < nt) stage(t + 1);   // issue next-tile loads before compute
    const int sl = t & 1;
    bf16x8 a[4], b[4];
    #pragma unroll
    for (int f = 0; f < 4; ++f) {
      const int ra = wr + f * 16 + (lane & 15);
      a[f] = *(const bf16x8*)&As[sl][ra * 32 + ((lane >> 4) ^ ((ra >> 1) & 3)) * 8];
      const int rb = wc + f * 16 + (lane & 15);
      b[f] = *(const bf16x8*)&Bs[sl][rb * 32 + ((lane >> 4) ^ ((rb >> 1) & 3)) * 8];
    }
    #pragma unroll
    for (int fr = 0; fr < 4; ++fr)
      #pragma unroll
      for (int fc = 0; fc < 4; ++fc)
        acc[fr][fc] = __builtin_amdgcn_mfma_f32_16x16x32_bf16(a[fr], b[fc], acc[fr][fc], 0, 0, 0);
    __syncthreads();   // drains this iter's stage + all waves done with buf[sl]
  }

  const int orow0 = brow + wr + (lane >> 4) * 4;
  const int ocol0 = bcol + wc + (lane & 15);

  if (EPI == 0 && p.vtrans && bz == 2) {
    // V projection written transposed: Vt[(b*DM + col)][s], s = row % SEQ
    #pragma unroll
    for (int fr = 0; fr < 4; ++fr) {
      const int row0 = orow0 + fr * 16;
      const int bq = row0 >> 11, s0 = row0 & (SEQ - 1);
      #pragma unroll
      for (int fc = 0; fc < 4; ++fc) {
        const int col = ocol0 + fc * 16;
        const float bvv = bias[col];
        u16x4 o;
        #pragma unroll
        for (int r = 0; r < 4; ++r) o[r] = f2b(acc[fr][fc][r] + bvv);
        *(u16x4*)((u16*)outv + (size_t)(bq * DM + col) * SEQ + s0) = o;
      }
    }
    return;
  }

  // 0.125 (1/sqrt(64)) * log2(e) — see attn (exp2-domain softmax)
  const float oscale = (EPI == 0 && p.vtrans && bz == 0) ? 0.18033688011112042f : 1.0f;

  #pragma unroll
  for (int fr = 0; fr < 4; ++fr) {
    #pragma unroll
    for (int fc = 0; fc < 4; ++fc) {
      const int col = ocol0 + fc * 16;
      const float bvv = (EPI == 3) ? 0.0f : bias[col];
      #pragma unroll
      for (int r = 0; r < 4; ++r) {
        const int row = orow0 + fr * 16 + r;
        const size_t idx = (size_t)row * N + col;
        float v = acc[fr][fc][r] + bvv;
        if (EPI == 0) {
          ((u16*)outv)[idx] = f2b(v * oscale);
        } else if (EPI == 1) {
          float ge = 0.5f * v * (1.0f + erff(v * 0.70710678118654752f));
          ((u16*)outv)[idx] = f2b(ge);
        } else if (EPI == 2) {
          ((float*)outv)[idx] = v + resid[idx];
        } else {
          ((u16*)outv)[idx] = f2bn(v);   // bf16 partial, combined later
        }
      }
    }
  }
}

// ---------------- flash attention, K-split x2 (flash-decoding) -------------
// R14 structure + R15 XCD swizzle. Partials Op now bf16 (relative 0.2%,
// cancels in the merge divide) — halves Op write+read traffic.
__global__ __launch_bounds__(128, 4)
void attn_kernel(const u16* __restrict__ Q, const u16* __restrict__ K,
                 const u16* __restrict__ Vt, u16* __restrict__ Opart,
                 float2* __restrict__ ML, int ktps) {
  __shared__ __align__(16) u16 Ks[64 * 64];    // [k][d]
  __shared__ __align__(16) u16 Vts[64 * 64];   // [d][k]
  const int tid = threadIdx.x, lane = tid & 63, w = tid >> 6;

  const int orig = xcd_orig(blockIdx.x, gridDim.x);
  const int bxq = orig & 31;            // q-block (SEQ/64 = 32)
  const int bh = (orig >> 5) & 31;      // b*16 + h
  const int kvh = orig >> 10;           // key split

  const int b = bh >> 4, h = bh & 15;
  const int q0 = bxq * 64 + w * 32;     // wave's q base
  const size_t base = (size_t)b * SEQ * DM + (size_t)h * DH;
  const size_t vbase = (size_t)(b * DM + h * DH) * SEQ;
  u16* __restrict__ Op = Opart + (size_t)kvh * MROWS * DM;
  float2* __restrict__ mlp = ML + (size_t)kvh * 2 * NH * SEQ;

  const int l31 = lane & 31, hi = lane >> 5, l7 = l31 & 7;

  // Q fragments (B-operand): col=q=l31, k(d) = dt*16 + hi*8 + j
  bf16x8 qf[4];
  {
    const size_t qrow = base + (size_t)(q0 + l31) * DM;
    #pragma unroll
    for (int dt = 0; dt < 4; ++dt)
      qf[dt] = *(const bf16x8*)&Q[qrow + dt * 16 + hi * 8];
  }

  f32x16 oacc[2] = {};   // d-tiles 0-31, 32-63
  float mq = -1e30f, lq = 0.0f;   // for q = q0 + l31 (column layout)

  for (int kt = kvh * ktps; kt < (kvh + 1) * ktps; ++kt) {
    // stage K[64k][64d] and Vt[64d][64k], swizzled chunk = c ^ (row&7)
    #pragma unroll
    for (int i = 0; i < 4; ++i) {
      const int r0 = w * 32 + i * 8;            // wave-uniform LDS base row
      const int row = r0 + (lane >> 3);
      const int ch = ((lane & 7) ^ (row & 7)) * 8;
      gl_lds16(&K[base + (size_t)(kt * 64 + row) * DM + ch], &Ks[r0 * 64]);
      gl_lds16(&Vt[vbase + (size_t)row * SEQ + kt * 64 + ch], &Vts[r0 * 64]);
    }
    __syncthreads();

    #pragma unroll
    for (int sub = 0; sub < 2; ++sub) {         // 32-key sub-blocks
      // S^T (log2 domain) = sum_dt mfma32(Kfrag, Qfrag)
      f32x16 sacc = {};
      __builtin_amdgcn_s_setprio(1);
      #pragma unroll
      for (int dt = 0; dt < 4; ++dt) {
        bf16x8 kf = *(const bf16x8*)&Ks[(sub * 32 + l31) * 64 + (((dt << 1) | hi) ^ l7) * 8];
        sacc = __builtin_amdgcn_mfma_f32_32x32x16_bf16(kf, qf[dt], sacc, 0, 0, 0);
      }
      __builtin_amdgcn_s_setprio(0);

      // column max for q = l31 (serial chain + cross-half exchange)
      float tm = sacc[0];
      #pragma unroll
      for (int r = 1; r < 16; ++r) tm = fmaxf(tm, sacc[r]);
      tm = fmaxf(tm, __shfl_xor(tm, 32, 64));

      if (__any(tm > mq + 11.5f)) {
        const float mnew = fmaxf(mq, tm);
        const float fs = ex2(mq - mnew);
        mq = mnew;
        lq *= fs;
        #pragma unroll
        for (int r = 0; r < 16; ++r) {
          const float fsr = __shfl(fs, (r & 3) + 8 * (r >> 2) + 4 * hi, 64);
          oacc[0][r] *= fsr;
          oacc[1][r] *= fsr;
        }
      }

      // exp2 + pack into PV A-fragments (two k-slots of 16)
      uint32_t wd[2][4];
      float ps = 0.0f;
      #pragma unroll
      for (int half = 0; half < 2; ++half) {
        float p[8];
        #pragma unroll
        for (int j = 0; j < 8; ++j) {
          p[j] = ex2(sacc[half * 8 + j] - mq);
          ps += p[j];
        }
        const uint32_t a = pk2(p[0], p[1]), c = pk2(p[2], p[3]);
        const uint32_t bb = pk2(p[4], p[5]), d = pk2(p[6], p[7]);
        const uint32_t xa = (uint32_t)__shfl_xor((int)a, 32, 64);
        const uint32_t xb = (uint32_t)__shfl_xor((int)bb, 32, 64);
        const uint32_t xc = (uint32_t)__shfl_xor((int)c, 32, 64);
        const uint32_t xd = (uint32_t)__shfl_xor((int)d, 32, 64);
        wd[half][0] = hi ? xb : a;
        wd[half][1] = hi ? xd : c;
        wd[half][2] = hi ? bb : xa;
        wd[half][3] = hi ? d : xc;
      }
      lq += ps;
      bf16x8 pa0, pa1;
      #pragma unroll
      for (int j = 0; j < 4; ++j) {
        ((uint32_t*)&pa0)[j] = wd[0][j];
        ((uint32_t*)&pa1)[j] = wd[1][j];
      }

      // PV: oacc[dt] += pa[ks] * V[ks][dt]
      __builtin_amdgcn_s_setprio(1);
      #pragma unroll
      for (int dt = 0; dt < 2; ++dt) {
        #pragma unroll
        for (int ks = 0; ks < 2; ++ks) {
          bf16x8 vf = *(const bf16x8*)&Vts[(dt * 32 + l31) * 64 +
                                           (((sub << 2) | (ks << 1) | hi) ^ l7) * 8];
          oacc[dt] = __builtin_amdgcn_mfma_f32_32x32x16_bf16(ks ? pa1 : pa0, vf, oacc[dt], 0, 0, 0);
        }
      }
      __builtin_amdgcn_s_setprio(0);
    }
    __syncthreads();
  }

  // write unnormalized bf16 partials + (m, l) per q  (m in log2 domain)
  const float ltot = lq + __shfl_xor(lq, 32, 64);
  #pragma unroll
  for (int r = 0; r < 16; ++r) {
    const int crow = (r & 3) + 8 * (r >> 2) + 4 * hi;
    const size_t orow = base + (size_t)(q0 + crow) * DM;
    Op[orow + l31]      = f2bn(oacc[0][r]);
    Op[orow + 32 + l31] = f2bn(oacc[1][r]);
  }
  if (hi == 0) mlp[(size_t)bh * SEQ + q0 + l31] = make_float2(mq, ltot);
}

// ---------------- attn merge (2-way, bf16 partials, log2-domain m) ---------
__global__ __launch_bounds__(256)
void attn_merge(const u16x4* __restrict__ Op0, const u16x4* __restrict__ Op1,
                const float2* __restrict__ ML, u16* __restrict__ ao) {
  const int row = blockIdx.x, tid = threadIdx.x;
  const int idx4 = row * (DM / 4) + tid;
  const int bh = ((row >> 11) << 4) | (tid >> 4);   // b*16 + h
  const int s = row & (SEQ - 1);
  const float2 a = ML[(size_t)bh * SEQ + s];
  const float2 c = ML[(size_t)(2 * NH) * SEQ + (size_t)bh * SEQ + s];
  const float m = fmaxf(a.x, c.x);
  const float f0 = ex2(a.x - m), f1 = ex2(c.x - m);
  const float inv = 1.0f / (a.y * f0 + c.y * f1);
  const u16x4 o0 = Op0[idx4], o1 = Op1[idx4];
  u16x4 o;
  o[0] = f2bn((b2f(o0[0]) * f0 + b2f(o1[0]) * f1) * inv);
  o[1] = f2bn((b2f(o0[1]) * f0 + b2f(o1[1]) * f1) * inv);
  o[2] = f2bn((b2f(o0[2]) * f0 + b2f(o1[2]) * f1) * inv);
  o[3] = f2bn((b2f(o0[3]) * f0 + b2f(o1[3]) * f1) * inv);
  ((u16x4*)ao)[idx4] = o;
}

// ---------------------------------------------------------------------------
extern "C" void kernel_launch(void* const* d_in, const int* in_sizes, int n_in,
                              void* d_out, int out_size, void* d_ws, size_t ws_size,
                              hipStream_t stream) {
  const float* x    = (const float*)d_in[0];
  const float* Wq   = (const float*)d_in[1];
  const float* bq   = (const float*)d_in[2];
  const float* Wk   = (const float*)d_in[3];
  const float* bk   = (const float*)d_in[4];
  const float* Wv   = (const float*)d_in[5];
  const float* bv   = (const float*)d_in[6];
  const float* Wo   = (const float*)d_in[7];
  const float* bo   = (const float*)d_in[8];
  const float* ln1g = (const float*)d_in[9];
  const float* ln1b = (const float*)d_in[10];
  const float* W1   = (const float*)d_in[11];
  const float* b1   = (const float*)d_in[12];
  const float* W2   = (const float*)d_in[13];
  const float* b2   = (const float*)d_in[14];
  const float* ln2g = (const float*)d_in[15];
  const float* ln2b = (const float*)d_in[16];
  float* out = (float*)d_out;

  char* wsb = (char*)d_ws;
  size_t off = 0;
  auto alloc = [&](size_t bytes) -> char* {
    char* pp = wsb + off;
    off += (bytes + 255) & ~(size_t)255;
    return pp;
  };
  u16* Wq_b = (u16*)alloc((size_t)DM * DM * 2);
  u16* Wk_b = (u16*)alloc((size_t)DM * DM * 2);
  u16* Wv_b = (u16*)alloc((size_t)DM * DM * 2);
  u16* Wo_b = (u16*)alloc((size_t)DM * DM * 2);
  u16* W1_b = (u16*)alloc((size_t)DFF * DM * 2);
  u16* W2_b = (u16*)alloc((size_t)DM * DFF * 2);
  u16* xn   = (u16*)alloc((size_t)MROWS * DM * 2);
  u16* qb   = (u16*)alloc((size_t)MROWS * DM * 2);
  u16* kb   = (u16*)alloc((size_t)MROWS * DM * 2);
  u16* vt   = (u16*)alloc((size_t)MROWS * DM * 2);  // transposed V
  u16* ao   = (u16*)alloc((size_t)MROWS * DM * 2);  // attn out, then LN2 out
  float2* ml = (float2*)alloc((size_t)2 * 2 * NH * SEQ * sizeof(float2));
  u16* h1   = (u16*)alloc((size_t)MROWS * DFF * 2); // FFN hidden; attn Op earlier
  u16* pX = (u16*)alloc((size_t)MROWS * DM * 2);
  u16* pY = (u16*)alloc((size_t)MROWS * DM * 2);
  const bool ws_x4 = (off <= ws_size);

  // bf16 partial buffers (8 MB each) overlaid on dead regions:
  u16* pA = xn;                       // xn (8 MB) — dead during O-proj & FFN2
  u16* pB = kb;                       // kb (8 MB)
  u16* pC = h1;                       // h1 lower — dead during O-proj
  u16* pD = h1 + (size_t)MROWS * DM;  // h1 upper
  u16* attnOp = h1;                   // attention x2 bf16 partials (16 MB)

  // 1. convert weights to bf16
  CvtArgs ca;
  ca.src[0] = Wq; ca.dst[0] = Wq_b; ca.n4[0] = DM * DM / 4;
  ca.src[1] = Wk; ca.dst[1] = Wk_b; ca.n4[1] = DM * DM / 4;
  ca.src[2] = Wv; ca.dst[2] = Wv_b; ca.n4[2] = DM * DM / 4;
  ca.src[3] = Wo; ca.dst[3] = Wo_b; ca.n4[3] = DM * DM / 4;
  ca.src[4] = W1; ca.dst[4] = W1_b; ca.n4[4] = DFF * DM / 4;
  ca.src[5] = W2; ca.dst[5] = W2_b; ca.n4[5] = DM * DFF / 4;
  cvt_kernel<<<2048, 256, 0, stream>>>(ca);

  // 2. LN1
  ln_kernel<<<MROWS, 256, 0, stream>>>(x, ln1g, ln1b, xn);

  // 3. QKV projections (z-fused; V transposed; Q pre-scaled 0.125*log2e)
  GemmPtrs pq = {};
  pq.W[0] = Wq_b; pq.W[1] = Wk_b; pq.W[2] = Wv_b;
  pq.bias[0] = bq; pq.bias[1] = bk; pq.bias[2] = bv;
  pq.out[0] = qb; pq.out[1] = kb; pq.out[2] = vt;
  pq.vtrans = 1;
  gemm_bt<0><<<(DM / 128) * (MROWS / 128) * 3, 256, 0, stream>>>(xn, pq, MROWS, DM, DM, DM);

  // 4. attention, K-split x2 -> bf16 partials + (m,l); merge -> ao (bf16)
  attn_kernel<<<(SEQ / 64) * 2 * NH * 2, 128, 0, stream>>>(qb, kb, vt, attnOp, ml,
                                                           SEQ / 64 / 2);
  attn_merge<<<MROWS, 256, 0, stream>>>((const u16x4*)attnOp,
                                        (const u16x4*)(attnOp + (size_t)MROWS * DM),
                                        (const float2*)ml, ao);

  // 5. output projection, K-split x4 -> bf16 partials; fused combine+LN2
  GemmPtrs po = {};
  po.W[0] = po.W[1] = po.W[2] = po.W[3] = Wo_b;
  po.bias[0] = po.bias[1] = po.bias[2] = po.bias[3] = bo;
  po.out[0] = pA; po.out[1] = pB; po.out[2] = pC; po.out[3] = pD;
  gemm_bt<3><<<(DM / 128) * (MROWS / 128) * 4, 256, 0, stream>>>(ao, po, MROWS, DM, DM, DM / 4);
  combine4_ln_kernel<<<MROWS, 256, 0, stream>>>((const u16x4*)pA, (const u16x4*)pB,
                                                (const u16x4*)pC, (const u16x4*)pD,
                                                (const float4*)bo, (const float4*)x,
                                                (float4*)out, ln2g, ln2b, ao);

  // 6. FFN up + GELU (input: LN2 output in ao; h1 now free for FFN hidden)
  GemmPtrs p1 = {};
  p1.W[0] = W1_b; p1.bias[0] = b1; p1.out[0] = h1;
  gemm_bt<1><<<(DFF / 128) * (MROWS / 128), 256, 0, stream>>>(ao, p1, MROWS, DFF, DM, DM);

  // 7. FFN down, K-split (x4 if ws allows, else x2) -> bf16 partials -> combine
  if (ws_x4) {
    GemmPtrs p2 = {};
    p2.W[0] = p2.W[1] = p2.W[2] = p2.W[3] = W2_b;
    p2.bias[0] = p2.bias[1] = p2.bias[2] = p2.bias[3] = b2;
    p2.out[0] = pA; p2.out[1] = pB; p2.out[2] = pX; p2.out[3] = pY;
    gemm_bt<3><<<(DM / 128) * (MROWS / 128) * 4, 256, 0, stream>>>(h1, p2, MROWS, DM, DFF, DFF / 4);
    combine4_kernel<<<2048, 256, 0, stream>>>((const u16x4*)pA, (const u16x4*)pB,
                                              (const u16x4*)pX, (const u16x4*)pY,
                                              (const float4*)b2, (const float4*)out,
                                              (float4*)out, MROWS * DM / 4, DM / 4 - 1);
  } else {
    GemmPtrs p2 = {};
    p2.W[0] = p2.W[1] = W2_b;
    p2.bias[0] = p2.bias[1] = b2;
    p2.out[0] = pA; p2.out[1] = pB;
    gemm_bt<3><<<(DM / 128) * (MROWS / 128) * 2, 256, 0, stream>>>(h1, p2, MROWS, DM, DFF, DFF / 2);
    combine_kernel<<<2048, 256, 0, stream>>>((const u16x4*)pA, (const u16x4*)pB,
                                             (const float4*)b2, (const float4*)out,
                                             (float4*)out, MROWS * DM / 4, DM / 4 - 1);
  }
}